// Round 13
// baseline (70.301 us; speedup 1.0000x reference)
//
#include <hip/hip_runtime.h>
#include <hip/hip_bf16.h>
#include <cstddef>

#define B_  8
#define CQ  256
#define CC  512
#define N_  1024   // Hq*Wq
#define HQ  32
#define WQ  32
#define NH  8
#define HD  32

// gstats layout (floats): ctxS [0,16384) idx=(b*N+pos)*2+chH ; ctxS2 [16384,32768)
//                         qS [32768,40960) idx=b*N+pos ; qS2 [40960,49152)
#define GS_CTXS2 16384
#define GS_QS    32768
#define GS_QS2   40960

typedef __bf16 bf16x8 __attribute__((ext_vector_type(8)));
typedef float f32x4 __attribute__((ext_vector_type(4)));
typedef float f32x16 __attribute__((ext_vector_type(16)));
typedef unsigned int uint4v __attribute__((ext_vector_type(4)));
typedef unsigned short ushort8 __attribute__((ext_vector_type(8)));
typedef unsigned short ushort4v __attribute__((ext_vector_type(4)));

__device__ __forceinline__ unsigned short f2bf(float x) {
    return __builtin_bit_cast(unsigned short, __float2bfloat16(x));
}
__device__ __forceinline__ float bf2f(unsigned short x) {
    return __bfloat162float(__builtin_bit_cast(__hip_bfloat16, x));
}
__device__ __forceinline__ bf16x8 ldb8(const unsigned short* p) {
    return __builtin_bit_cast(bf16x8, *(const ushort8*)p);
}

// ---------------------------------------------------------------------------
// prep_k (1664 blocks x 256):
//   [0,512):     weight transpose f32->bf16 (4 matrices)
//   [512,1536):  pool(context) -> RAW bf16 cn (B,N,Cc) + partial LN stats.
//                1024 blocks = 2 channel-halves (stats slot chH), 16 pos each,
//                128B contiguous lane-octet segments, 16-load chains.
//   [1536,1664): query -> RAW bf16 qn (B,N,Cq) transposed + LN stats.
// LN itself is applied downstream in proj_all's A-staging.
// ---------------------------------------------------------------------------
__global__ __launch_bounds__(256) void prep_k(
    const float* __restrict__ query, const float* __restrict__ context,
    const float* __restrict__ Wq, const float* __restrict__ Wk,
    const float* __restrict__ Wv, const float* __restrict__ Wo,
    __hip_bfloat16* __restrict__ Wqt, __hip_bfloat16* __restrict__ Wkt,
    __hip_bfloat16* __restrict__ Wvt, __hip_bfloat16* __restrict__ Wot,
    __hip_bfloat16* __restrict__ qn, __hip_bfloat16* __restrict__ cn,
    float* __restrict__ gstats) {
    __shared__ float T[32][33];
    __shared__ float SsA[32][16];
    __shared__ float S2A[32][16];
    __shared__ float SsB[16][64];
    __shared__ float S2B[16][64];

    const int bid = blockIdx.x;
    const int tid = threadIdx.x;

    if (bid < 512) {
        // ---------------- weight transpose ----------------
        const int x = bid & 15, y = (bid >> 4) & 7, z = bid >> 7;
        const float* W; __hip_bfloat16* Wt; int K;
        switch (z) {
            case 0: W = Wq; Wt = Wqt; K = CQ; break;
            case 1: W = Wk; Wt = Wkt; K = CC; break;
            case 2: W = Wv; Wt = Wvt; K = CC; break;
            default: W = Wo; Wt = Wot; K = CQ; break;
        }
        const int k0 = x * 32;
        if (k0 >= K) return;
        const int c0 = y * 32;
        const int tx = tid & 31, ty = tid >> 5;
        #pragma unroll
        for (int i = 0; i < 4; ++i) {
            const int r = ty + 8 * i;
            T[r][tx] = W[(size_t)(k0 + r) * CQ + c0 + tx];
        }
        __syncthreads();
        #pragma unroll
        for (int i = 0; i < 4; ++i) {
            const int r = ty + 8 * i;
            Wt[(size_t)(c0 + r) * K + k0 + tx] = __float2bfloat16(T[tx][r]);
        }
    } else if (bid < 1536) {
        // ------- pool(context) raw + partial stats: 1024 blocks -------
        // block = (chH 0..1, wqc2 0..1, hq 0..31, b 0..7)
        const int u    = bid - 512;
        const int chH  = u & 1, wqc2 = (u >> 1) & 1, hq = (u >> 2) & 31, b = u >> 7;
        const int pp   = tid & 7;         // position-pair 0..7 (pos 2pp, 2pp+1)
        const int cg   = tid >> 3;        // channel group 0..31 (8 ch each)
        const int ch0  = chH * 256 + cg * 8;

        const float* Cb = context + ((size_t)b * CC + ch0) * 4096
                        + (size_t)(2 * hq) * 64 + (32 * wqc2 + 4 * pp);
        float pv0[8], pv1[8];
        float ss0 = 0.f, ss1 = 0.f, s20 = 0.f, s21 = 0.f;
        #pragma unroll
        for (int i = 0; i < 8; ++i) {
            const float4 r0 = *(const float4*)(Cb + (size_t)i * 4096);
            const float4 r1 = *(const float4*)(Cb + (size_t)i * 4096 + 64);
            const float v0 = (r0.x + r0.y + r1.x + r1.y) * 0.25f;
            const float v1 = (r0.z + r0.w + r1.z + r1.w) * 0.25f;
            pv0[i] = v0; pv1[i] = v1;
            ss0 += v0; s20 += v0 * v0;
            ss1 += v1; s21 += v1 * v1;
        }
        SsA[cg][2 * pp]     = ss0; S2A[cg][2 * pp]     = s20;
        SsA[cg][2 * pp + 1] = ss1; S2A[cg][2 * pp + 1] = s21;

        // raw bf16 writes (independent of stats)
        const int pos0 = hq * 32 + wqc2 * 16 + 2 * pp;
        unsigned short* dst = (unsigned short*)cn
            + ((size_t)b * N_ + pos0) * CC + ch0;
        ushort8 o0, o1;
        #pragma unroll
        for (int i = 0; i < 8; ++i) { o0[i] = f2bf(pv0[i]); o1[i] = f2bf(pv1[i]); }
        *(ushort8*)(dst)      = o0;
        *(ushort8*)(dst + CC) = o1;

        __syncthreads();
        if (tid < 16) {
            float ts = 0.f, t2 = 0.f;
            #pragma unroll
            for (int i = 0; i < 32; ++i) { ts += SsA[i][tid]; t2 += S2A[i][tid]; }
            const int pos = hq * 32 + wqc2 * 16 + tid;
            const size_t sidx = ((size_t)b * N_ + pos) * 2 + chH;
            gstats[sidx]            = ts;
            gstats[GS_CTXS2 + sidx] = t2;
        }
    } else {
        // --------- query raw + stats: 128 blocks ---------
        const int u  = bid - 1536;
        const int nt = u & 15, b = u >> 4;
        const int nq = tid & 15;          // n-quad: positions 4nq..4nq+3
        const int cg = tid >> 4;          // channel group 0..15 (16 ch each)
        const int ch0 = cg * 16;
        const int nb  = nt * 64 + 4 * nq;

        const float* Qb = query + ((size_t)b * CQ + ch0) * N_ + nb;
        float qv[64];
        float ps[4] = {0.f, 0.f, 0.f, 0.f};
        float p2[4] = {0.f, 0.f, 0.f, 0.f};
        #pragma unroll
        for (int i = 0; i < 16; ++i) {
            const float4 v = *(const float4*)(Qb + (size_t)i * N_);
            qv[4 * i + 0] = v.x; qv[4 * i + 1] = v.y;
            qv[4 * i + 2] = v.z; qv[4 * i + 3] = v.w;
            ps[0] += v.x; p2[0] += v.x * v.x;
            ps[1] += v.y; p2[1] += v.y * v.y;
            ps[2] += v.z; p2[2] += v.z * v.z;
            ps[3] += v.w; p2[3] += v.w * v.w;
        }
        #pragma unroll
        for (int j = 0; j < 4; ++j) {
            SsB[cg][4 * nq + j] = ps[j];
            S2B[cg][4 * nq + j] = p2[j];
        }

        // raw bf16 transposed writes
        #pragma unroll
        for (int j = 0; j < 4; ++j) {
            ushort8 o0, o1;
            #pragma unroll
            for (int i = 0; i < 8; ++i) o0[i] = f2bf(qv[4 * i + j]);
            #pragma unroll
            for (int i = 0; i < 8; ++i) o1[i] = f2bf(qv[4 * (8 + i) + j]);
            unsigned short* dst = (unsigned short*)qn
                + ((size_t)b * N_ + nb + j) * CQ + ch0;
            *(ushort8*)(dst)     = o0;
            *(ushort8*)(dst + 8) = o1;
        }

        __syncthreads();
        if (tid < 64) {
            float ts = 0.f, t2 = 0.f;
            #pragma unroll
            for (int i = 0; i < 16; ++i) { ts += SsB[i][tid]; t2 += S2B[i][tid]; }
            const size_t qidx = (size_t)b * N_ + nt * 64 + tid;
            gstats[GS_QS  + qidx] = ts;
            gstats[GS_QS2 + qidx] = t2;
        }
    }
}

// ---------------------------------------------------------------------------
// proj_all_k: Q projection (z>=8) and fused K+V projection (z<8).
// LN is applied HERE, in the A-staging step, from prep's raw values + stats
// (mu/rs computed once per thread-row). Reg-staged global prefetch; V columns
// PERMUTED per 16-block so attention reads contiguous PV B-frags.
// grid (16, 4, 16), block 256.
// ---------------------------------------------------------------------------
__global__ __launch_bounds__(256) void proj_all_k(
    const __hip_bfloat16* __restrict__ qn, const __hip_bfloat16* __restrict__ cn,
    const __hip_bfloat16* __restrict__ Wqt, const __hip_bfloat16* __restrict__ Wkt,
    const __hip_bfloat16* __restrict__ Wvt,
    const float* __restrict__ bq, const float* __restrict__ bk,
    const float* __restrict__ bv,
    const float* __restrict__ gq, const float* __restrict__ betq,
    const float* __restrict__ gc, const float* __restrict__ betc,
    const float* __restrict__ gstats,
    __hip_bfloat16* __restrict__ Qb, __hip_bfloat16* __restrict__ Kb,
    __hip_bfloat16* __restrict__ Vt, float qsc) {
    __shared__ unsigned short As[64][40];
    __shared__ unsigned short B1[64][40];
    __shared__ unsigned short B2[64][40];

    const int zz = blockIdx.z;
    const int n0 = blockIdx.x * 64;
    const int c0 = blockIdx.y * 64;
    const int tid = threadIdx.x;
    const int wid = tid >> 6, lane = tid & 63;
    const int lg = lane >> 4, ln = lane & 15;
    const int wn0 = (wid & 1) * 32, wc0 = (wid >> 1) * 32;
    const int sr = tid >> 2;
    const int sk = (tid & 3) * 8;

    if (zz >= 8) {
        // ---------------- Q projection (K = 256) ----------------
        const int b = zz - 8;
        const int row = n0 + sr;
        const float Ssum  = gstats[GS_QS  + (size_t)b * N_ + row];
        const float S2sum = gstats[GS_QS2 + (size_t)b * N_ + row];
        const float mu = Ssum * (1.f / CQ);
        const float rs = rsqrtf(S2sum * (1.f / CQ) - mu * mu + 1e-5f);

        const unsigned short* Ab = (const unsigned short*)qn + ((size_t)b * N_ + n0) * CQ;
        const unsigned short* Wb = (const unsigned short*)Wqt + (size_t)c0 * CQ;
        f32x4 acc[2][2] = {};
        ushort8 ra = *(const ushort8*)(Ab + (size_t)sr * CQ + sk);
        ushort8 rw = *(const ushort8*)(Wb + (size_t)sr * CQ + sk);
        for (int t = 0; t < 8; ++t) {
            const int kof = t * 32 + sk;
            const float4 g0 = *(const float4*)&gq[kof];
            const float4 g1 = *(const float4*)&gq[kof + 4];
            const float4 e0 = *(const float4*)&betq[kof];
            const float4 e1 = *(const float4*)&betq[kof + 4];
            ushort8 st;
            st[0] = f2bf((bf2f(ra[0]) - mu) * rs * g0.x + e0.x);
            st[1] = f2bf((bf2f(ra[1]) - mu) * rs * g0.y + e0.y);
            st[2] = f2bf((bf2f(ra[2]) - mu) * rs * g0.z + e0.z);
            st[3] = f2bf((bf2f(ra[3]) - mu) * rs * g0.w + e0.w);
            st[4] = f2bf((bf2f(ra[4]) - mu) * rs * g1.x + e1.x);
            st[5] = f2bf((bf2f(ra[5]) - mu) * rs * g1.y + e1.y);
            st[6] = f2bf((bf2f(ra[6]) - mu) * rs * g1.z + e1.z);
            st[7] = f2bf((bf2f(ra[7]) - mu) * rs * g1.w + e1.w);
            *(ushort8*)&As[sr][sk] = st;
            *(ushort8*)&B1[sr][sk] = rw;
            __syncthreads();
            if (t < 7) {
                ra = *(const ushort8*)(Ab + (size_t)sr * CQ + (t + 1) * 32 + sk);
                rw = *(const ushort8*)(Wb + (size_t)sr * CQ + (t + 1) * 32 + sk);
            }
            bf16x8 a[2], w[2];
            #pragma unroll
            for (int i = 0; i < 2; ++i) a[i] = ldb8(&As[wn0 + 16 * i + ln][8 * lg]);
            #pragma unroll
            for (int j = 0; j < 2; ++j) w[j] = ldb8(&B1[wc0 + 16 * j + ln][8 * lg]);
            #pragma unroll
            for (int i = 0; i < 2; ++i)
                #pragma unroll
                for (int j = 0; j < 2; ++j)
                    acc[i][j] = __builtin_amdgcn_mfma_f32_16x16x32_bf16(a[i], w[j], acc[i][j], 0, 0, 0);
            __syncthreads();
        }
        #pragma unroll
        for (int j = 0; j < 2; ++j) {
            const int co = c0 + wc0 + 16 * j + ln;
            const int h = co >> 5, d = co & 31;
            const float bb = bq[co];
            #pragma unroll
            for (int i = 0; i < 2; ++i)
                #pragma unroll
                for (int r = 0; r < 4; ++r) {
                    const int n = n0 + wn0 + 16 * i + 4 * lg + r;
                    Qb[(((size_t)b * NH + h) * N_ + n) * HD + d] =
                        __float2bfloat16((acc[i][j][r] + bb) * qsc);
                }
        }
    } else {
        // ---------------- K + V projection (K = 512) ----------------
        const int b = zz;
        const int row = n0 + sr;
        const size_t sidx = ((size_t)b * N_ + row) * 2;
        const float Ssum  = gstats[sidx] + gstats[sidx + 1];
        const float S2sum = gstats[GS_CTXS2 + sidx] + gstats[GS_CTXS2 + sidx + 1];
        const float mu = Ssum * (1.f / CC);
        const float rs = rsqrtf(S2sum * (1.f / CC) - mu * mu + 1e-5f);

        const unsigned short* Ab  = (const unsigned short*)cn + ((size_t)b * N_ + n0) * CC;
        const unsigned short* Wkb = (const unsigned short*)Wkt + (size_t)c0 * CC;
        const unsigned short* Wvb = (const unsigned short*)Wvt + (size_t)c0 * CC;
        f32x4 accK[2][2] = {};
        f32x4 accV[2][2] = {};
        ushort8 ra = *(const ushort8*)(Ab  + (size_t)sr * CC + sk);
        ushort8 rk = *(const ushort8*)(Wkb + (size_t)sr * CC + sk);
        ushort8 rv = *(const ushort8*)(Wvb + (size_t)sr * CC + sk);
        for (int t = 0; t < 16; ++t) {
            const int kof = t * 32 + sk;
            const float4 g0 = *(const float4*)&gc[kof];
            const float4 g1 = *(const float4*)&gc[kof + 4];
            const float4 e0 = *(const float4*)&betc[kof];
            const float4 e1 = *(const float4*)&betc[kof + 4];
            ushort8 st;
            st[0] = f2bf((bf2f(ra[0]) - mu) * rs * g0.x + e0.x);
            st[1] = f2bf((bf2f(ra[1]) - mu) * rs * g0.y + e0.y);
            st[2] = f2bf((bf2f(ra[2]) - mu) * rs * g0.z + e0.z);
            st[3] = f2bf((bf2f(ra[3]) - mu) * rs * g0.w + e0.w);
            st[4] = f2bf((bf2f(ra[4]) - mu) * rs * g1.x + e1.x);
            st[5] = f2bf((bf2f(ra[5]) - mu) * rs * g1.y + e1.y);
            st[6] = f2bf((bf2f(ra[6]) - mu) * rs * g1.z + e1.z);
            st[7] = f2bf((bf2f(ra[7]) - mu) * rs * g1.w + e1.w);
            *(ushort8*)&As[sr][sk] = st;
            *(ushort8*)&B1[sr][sk] = rk;
            *(ushort8*)&B2[sr][sk] = rv;
            __syncthreads();
            if (t < 15) {
                ra = *(const ushort8*)(Ab  + (size_t)sr * CC + (t + 1) * 32 + sk);
                rk = *(const ushort8*)(Wkb + (size_t)sr * CC + (t + 1) * 32 + sk);
                rv = *(const ushort8*)(Wvb + (size_t)sr * CC + (t + 1) * 32 + sk);
            }
            bf16x8 a[2], wk[2], wv[2];
            #pragma unroll
            for (int i = 0; i < 2; ++i) {
                a[i]  = ldb8(&As[wn0 + 16 * i + ln][8 * lg]);
                wk[i] = ldb8(&B1[wc0 + 16 * i + ln][8 * lg]);
                wv[i] = ldb8(&B2[wc0 + 16 * i + ln][8 * lg]);
            }
            #pragma unroll
            for (int i = 0; i < 2; ++i)
                #pragma unroll
                for (int j = 0; j < 2; ++j) {
                    accK[i][j] = __builtin_amdgcn_mfma_f32_16x16x32_bf16(a[i], wk[j], accK[i][j], 0, 0, 0);
                    accV[i][j] = __builtin_amdgcn_mfma_f32_16x16x32_bf16(a[i], wv[j], accV[i][j], 0, 0, 0);
                }
            __syncthreads();
        }
        #pragma unroll
        for (int j = 0; j < 2; ++j) {
            const int co = c0 + wc0 + 16 * j + ln;
            const int h = co >> 5, d = co & 31;
            const float bbk = bk[co], bbv = bv[co];
            #pragma unroll
            for (int i = 0; i < 2; ++i) {
                const int nb = n0 + wn0 + 16 * i + 4 * lg;
                #pragma unroll
                for (int r = 0; r < 4; ++r)
                    Kb[(((size_t)b * NH + h) * N_ + nb + r) * HD + d] =
                        __float2bfloat16(accK[i][j][r] + bbk);
                ushort4v o;
                #pragma unroll
                for (int r = 0; r < 4; ++r) o[r] = f2bf(accV[i][j][r] + bbv);
                const int g  = (nb >> 2) & 3;
                const int gp = ((g & 1) << 1) | (g >> 1);
                const int nbp = (nb & ~15) | (gp << 2);
                *(ushort4v*)((unsigned short*)Vt + (((size_t)b * NH + h) * HD + d) * N_ + nbp) = o;
            }
        }
    }
}

// ---------------------------------------------------------------------------
// 32x32 swapped-QK^T flash attention, in-register max-free softmax,
// 4-way kv-split. grid (32, 64) XCD-swizzled.  [R12-exact]
// ---------------------------------------------------------------------------
__global__ __launch_bounds__(256) void attn32_k(
    const __hip_bfloat16* __restrict__ Q,
    const __hip_bfloat16* __restrict__ K,
    const __hip_bfloat16* __restrict__ Vt,
    __hip_bfloat16* __restrict__ O) {
    __shared__ float accS[3][64][20];
    __shared__ float lwS[3][64];

    const int lin = blockIdx.x + 32 * blockIdx.y;
    const int eff = (lin & 7) * 256 + (lin >> 3);   // 2048 blocks, 8 XCDs
    const int qt  = eff & 31;
    const int bh  = eff >> 5;
    const int b   = bh >> 3;
    const int h   = bh & 7;
    const int wid  = threadIdx.x >> 6;   // kv quarter 0..3
    const int lane = threadIdx.x & 63;
    const int l31  = lane & 31;
    const int hh   = lane >> 5;
    const int q0   = qt * 32;

    const unsigned short* Qp = (const unsigned short*)Q + ((size_t)bh * N_ + q0) * HD;
    const unsigned short* Kbb = (const unsigned short*)K + (size_t)bh * N_ * HD;
    const unsigned short* Vb = (const unsigned short*)Vt + ((size_t)bh * HD + l31) * N_;

    bf16x8 qB[2];
    #pragma unroll
    for (int m = 0; m < 2; ++m)
        qB[m] = ldb8(Qp + (size_t)l31 * HD + 16 * m + 8 * hh);

    const f32x16 Z = {0.f,0.f,0.f,0.f,0.f,0.f,0.f,0.f,
                      0.f,0.f,0.f,0.f,0.f,0.f,0.f,0.f};
    f32x16 acc = Z;
    float ls0 = 0.f, ls1 = 0.f, ls2 = 0.f, ls3 = 0.f;

    const int kvbase = wid * 256;
    const unsigned short* kp = Kbb + (size_t)(kvbase + l31) * HD + 8 * hh;
    const unsigned short* vp = Vb + kvbase + 8 * hh;

    bf16x8 kaA[2][4];
    #pragma unroll
    for (int j = 0; j < 4; ++j)
        kaA[0][j] = ldb8(kp + (j >> 1) * 1024 + (j & 1) * 16);

    #pragma unroll
    for (int st = 0; st < 4; ++st) {
        const int cur = st & 1;
        bf16x8 va[4];
        #pragma unroll
        for (int j = 0; j < 4; ++j)
            va[j] = ldb8(vp + st * 64 + 16 * j);
        if (st < 3) {
            const unsigned short* kp2 = kp + (size_t)(st + 1) * 2048;
            #pragma unroll
            for (int j = 0; j < 4; ++j)
                kaA[cur ^ 1][j] = ldb8(kp2 + (j >> 1) * 1024 + (j & 1) * 16);
        }

        f32x16 s0, s1;
        s0 = __builtin_amdgcn_mfma_f32_32x32x16_bf16(kaA[cur][0], qB[0], Z, 0, 0, 0);
        s0 = __builtin_amdgcn_mfma_f32_32x32x16_bf16(kaA[cur][1], qB[1], s0, 0, 0, 0);
        s1 = __builtin_amdgcn_mfma_f32_32x32x16_bf16(kaA[cur][2], qB[0], Z, 0, 0, 0);
        s1 = __builtin_amdgcn_mfma_f32_32x32x16_bf16(kaA[cur][3], qB[1], s1, 0, 0, 0);

        unsigned int pk[2][4][2];
        #pragma unroll
        for (int T = 0; T < 2; ++T) {
            float p[16];
            #pragma unroll
            for (int r = 0; r < 16; ++r)
                p[r] = __builtin_amdgcn_exp2f(T == 0 ? s0[r] : s1[r]);
            #pragma unroll
            for (int r = 0; r < 16; r += 4) {
                ls0 += p[r]; ls1 += p[r + 1]; ls2 += p[r + 2]; ls3 += p[r + 3];
            }
            #pragma unroll
            for (int c = 0; c < 4; ++c) {
                asm("v_cvt_pk_bf16_f32 %0, %1, %2"
                    : "=v"(pk[T][c][0]) : "v"(p[4 * c]), "v"(p[4 * c + 1]));
                asm("v_cvt_pk_bf16_f32 %0, %1, %2"
                    : "=v"(pk[T][c][1]) : "v"(p[4 * c + 2]), "v"(p[4 * c + 3]));
            }
        }

        #pragma unroll
        for (int w = 0; w < 4; ++w) {
            const int T = w >> 1, cp = w & 1;
            uint4v fu = {pk[T][2 * cp][0], pk[T][2 * cp][1],
                         pk[T][2 * cp + 1][0], pk[T][2 * cp + 1][1]};
            const bf16x8 pa = __builtin_bit_cast(bf16x8, fu);
            acc = __builtin_amdgcn_mfma_f32_32x32x16_bf16(pa, va[w], acc, 0, 0, 0);
        }
    }

    const float lsum = (ls0 + ls1) + (ls2 + ls3);
    const float lw = lsum + __shfl_xor(lsum, 32);

    if (wid > 0) {
        #pragma unroll
        for (int r4 = 0; r4 < 4; ++r4) {
            float4 v = {acc[4 * r4], acc[4 * r4 + 1], acc[4 * r4 + 2], acc[4 * r4 + 3]};
            *(float4*)&accS[wid - 1][lane][4 * r4] = v;
        }
        lwS[wid - 1][lane] = lw;
    }
    __syncthreads();
    if (wid == 0) {
        const float ltot = lw + lwS[0][lane] + lwS[1][lane] + lwS[2][lane];
        const float linv = 1.0f / ltot;
        #pragma unroll
        for (int r = 0; r < 16; ++r) {
            const int ql = (r & 3) + 8 * (r >> 2) + 4 * hh;
            const float vv = (acc[r] + accS[0][lane][r] + accS[1][lane][r]
                              + accS[2][lane][r]) * __shfl(linv, ql);
            O[((size_t)b * N_ + q0 + ql) * CQ + h * HD + l31] = __float2bfloat16(vv);
        }
    }
}

// ---------------------------------------------------------------------------
// Output projection + bias + residual with reg-staged prefetch.
// grid (16, 4, B), block 256.  [R9-exact]
// ---------------------------------------------------------------------------
__global__ __launch_bounds__(256) void out_proj_k(const __hip_bfloat16* __restrict__ Ob,
                              const __hip_bfloat16* __restrict__ Wot,
                              const float* __restrict__ bo,
                              const float* __restrict__ query,
                              float* __restrict__ out) {
    __shared__ unsigned short As[64][40];
    __shared__ unsigned short Bs[64][40];
    const int b  = blockIdx.z;
    const int n0 = blockIdx.x * 64;
    const int c0 = blockIdx.y * 64;
    const int tid = threadIdx.x;
    const int wid = tid >> 6, lane = tid & 63;
    const int lg = lane >> 4, ln = lane & 15;
    const int wn0 = (wid & 1) * 32, wc0 = (wid >> 1) * 32;

    const unsigned short* Ab = (const unsigned short*)Ob + ((size_t)b * N_ + n0) * CQ;
    const unsigned short* Wb = (const unsigned short*)Wot + (size_t)c0 * CQ;
    const int sr = tid >> 2;
    const int sk = (tid & 3) * 8;

    f32x4 acc[2][2] = {};
    ushort8 ra = *(const ushort8*)(Ab + (size_t)sr * CQ + sk);
    ushort8 rw = *(const ushort8*)(Wb + (size_t)sr * CQ + sk);

    for (int t = 0; t < 8; ++t) {
        *(ushort8*)&As[sr][sk] = ra;
        *(ushort8*)&Bs[sr][sk] = rw;
        __syncthreads();
        if (t < 7) {
            ra = *(const ushort8*)(Ab + (size_t)sr * CQ + (t + 1) * 32 + sk);
            rw = *(const ushort8*)(Wb + (size_t)sr * CQ + (t + 1) * 32 + sk);
        }
        bf16x8 a[2], w[2];
        #pragma unroll
        for (int i = 0; i < 2; ++i)
            a[i] = ldb8(&As[wn0 + 16 * i + ln][8 * lg]);
        #pragma unroll
        for (int j = 0; j < 2; ++j)
            w[j] = ldb8(&Bs[wc0 + 16 * j + ln][8 * lg]);
        #pragma unroll
        for (int i = 0; i < 2; ++i)
            #pragma unroll
            for (int j = 0; j < 2; ++j)
                acc[i][j] = __builtin_amdgcn_mfma_f32_16x16x32_bf16(a[i], w[j], acc[i][j], 0, 0, 0);
        __syncthreads();
    }

    #pragma unroll
    for (int j = 0; j < 2; ++j) {
        const int co = c0 + wc0 + 16 * j + ln;
        const float bb = bo[co];
        #pragma unroll
        for (int i = 0; i < 2; ++i) {
            const int nb = n0 + wn0 + 16 * i + 4 * lg;
            const float4 res = *(const float4*)&query[((size_t)b * CQ + co) * N_ + nb];
            float4 o;
            o.x = acc[i][j][0] + bb + res.x;
            o.y = acc[i][j][1] + bb + res.y;
            o.z = acc[i][j][2] + bb + res.z;
            o.w = acc[i][j][3] + bb + res.w;
            *(float4*)&out[((size_t)b * CQ + co) * N_ + nb] = o;
        }
    }
}

// ---------------------------------------------------------------------------
extern "C" void kernel_launch(void* const* d_in, const int* in_sizes, int n_in,
                              void* d_out, int out_size, void* d_ws, size_t ws_size,
                              hipStream_t stream) {
    const float* query   = (const float*)d_in[0];
    const float* context = (const float*)d_in[1];
    const float* Wq = (const float*)d_in[2];
    const float* bq = (const float*)d_in[3];
    const float* Wk = (const float*)d_in[4];
    const float* bk = (const float*)d_in[5];
    const float* Wv = (const float*)d_in[6];
    const float* bv = (const float*)d_in[7];
    const float* Wo = (const float*)d_in[8];
    const float* bo = (const float*)d_in[9];
    const float* gq   = (const float*)d_in[10];
    const float* betq = (const float*)d_in[11];
    const float* gc   = (const float*)d_in[12];
    const float* betc = (const float*)d_in[13];
    float* out = (float*)d_out;

    char* w = (char*)d_ws;
    __hip_bfloat16* qn  = (__hip_bfloat16*)w;  w += (size_t)B_ * N_ * CQ * 2;
    __hip_bfloat16* cn  = (__hip_bfloat16*)w;  w += (size_t)B_ * N_ * CC * 2;
    __hip_bfloat16* Qb  = (__hip_bfloat16*)w;  w += (size_t)B_ * NH * N_ * HD * 2;
    __hip_bfloat16* Kb  = (__hip_bfloat16*)w;  w += (size_t)B_ * NH * N_ * HD * 2;
    __hip_bfloat16* Vt  = (__hip_bfloat16*)w;  w += (size_t)B_ * NH * HD * N_ * 2;
    __hip_bfloat16* Ob  = (__hip_bfloat16*)w;  w += (size_t)B_ * N_ * CQ * 2;
    __hip_bfloat16* Wqt = (__hip_bfloat16*)w;  w += (size_t)CQ * CQ * 2;
    __hip_bfloat16* Wkt = (__hip_bfloat16*)w;  w += (size_t)CQ * CC * 2;
    __hip_bfloat16* Wvt = (__hip_bfloat16*)w;  w += (size_t)CQ * CC * 2;
    __hip_bfloat16* Wot = (__hip_bfloat16*)w;  w += (size_t)CQ * CQ * 2;
    float* gstats = (float*)w;                 w += (size_t)49152 * 4;

    prep_k<<<dim3(1664), 256, 0, stream>>>(query, context, Wq, Wk, Wv, Wo,
                                           Wqt, Wkt, Wvt, Wot, qn, cn, gstats);

    // scale includes log2(e) so the softmax exp becomes a bare v_exp_f32
    const float qsc = 0.17677669529663687f * 1.4426950408889634f;
    proj_all_k<<<dim3(16, 4, 16), 256, 0, stream>>>(qn, cn, Wqt, Wkt, Wvt,
                                                    bq, bk, bv,
                                                    gq, betq, gc, betc, gstats,
                                                    Qb, Kb, Vt, qsc);

    attn32_k<<<dim3(32, 64), 256, 0, stream>>>(Qb, Kb, Vt, Ob);

    out_proj_k<<<dim3(16, 4, 8), 256, 0, stream>>>(Ob, Wot, bo, query, out);
}

// Round 14
// 68.357 us; speedup vs baseline: 1.0284x; 1.0284x over previous
//
#include <hip/hip_runtime.h>
#include <hip/hip_bf16.h>
#include <cstddef>

#define B_  8
#define CQ  256
#define CC  512
#define N_  1024   // Hq*Wq
#define HQ  32
#define WQ  32
#define NH  8
#define HD  32

typedef __bf16 bf16x8 __attribute__((ext_vector_type(8)));
typedef float f32x4 __attribute__((ext_vector_type(4)));
typedef float f32x16 __attribute__((ext_vector_type(16)));
typedef unsigned int uint4v __attribute__((ext_vector_type(4)));
typedef unsigned short ushort8 __attribute__((ext_vector_type(8)));
typedef unsigned short ushort4v __attribute__((ext_vector_type(4)));

__device__ __forceinline__ unsigned short f2bf(float x) {
    return __builtin_bit_cast(unsigned short, __float2bfloat16(x));
}
__device__ __forceinline__ float bf2f(unsigned short x) {
    return __bfloat162float(__builtin_bit_cast(__hip_bfloat16, x));
}
__device__ __forceinline__ bf16x8 ldb8(const unsigned short* p) {
    return __builtin_bit_cast(bf16x8, *(const ushort8*)p);
}

// ---------------------------------------------------------------------------
// prep_k (1152 blocks x 256): [R9-exact + qraw bf16 residual copy]
//   [0,512):     weight transpose f32->bf16 (4 matrices)
//   [512,1024):  pool+LN(context) -> cn (B,N,Cc) bf16
//   [1024,1152): LN(query) -> qn (B,N,Cq) bf16 + raw bf16 qraw (B,Cq,N)
// ---------------------------------------------------------------------------
__global__ __launch_bounds__(256) void prep_k(
    const float* __restrict__ query, const float* __restrict__ context,
    const float* __restrict__ Wq, const float* __restrict__ Wk,
    const float* __restrict__ Wv, const float* __restrict__ Wo,
    const float* __restrict__ gq, const float* __restrict__ betq,
    const float* __restrict__ gc, const float* __restrict__ betc,
    __hip_bfloat16* __restrict__ Wqt, __hip_bfloat16* __restrict__ Wkt,
    __hip_bfloat16* __restrict__ Wvt, __hip_bfloat16* __restrict__ Wot,
    __hip_bfloat16* __restrict__ qn, __hip_bfloat16* __restrict__ cn,
    __hip_bfloat16* __restrict__ qraw) {
    __shared__ float T[32][33];
    __shared__ float SsA[32][16];
    __shared__ float S2A[32][16];
    __shared__ float SsB[16][64];
    __shared__ float S2B[16][64];
    __shared__ float Mu[64], Rs[64];

    const int bid = blockIdx.x;
    const int tid = threadIdx.x;

    if (bid < 512) {
        // ---------------- weight transpose ----------------
        const int x = bid & 15, y = (bid >> 4) & 7, z = bid >> 7;
        const float* W; __hip_bfloat16* Wt; int K;
        switch (z) {
            case 0: W = Wq; Wt = Wqt; K = CQ; break;
            case 1: W = Wk; Wt = Wkt; K = CC; break;
            case 2: W = Wv; Wt = Wvt; K = CC; break;
            default: W = Wo; Wt = Wot; K = CQ; break;
        }
        const int k0 = x * 32;
        if (k0 >= K) return;
        const int c0 = y * 32;
        const int tx = tid & 31, ty = tid >> 5;
        #pragma unroll
        for (int i = 0; i < 4; ++i) {
            const int r = ty + 8 * i;
            T[r][tx] = W[(size_t)(k0 + r) * CQ + c0 + tx];
        }
        __syncthreads();
        #pragma unroll
        for (int i = 0; i < 4; ++i) {
            const int r = ty + 8 * i;
            Wt[(size_t)(c0 + r) * K + k0 + tx] = __float2bfloat16(T[tx][r]);
        }
    } else if (bid < 1024) {
        // ------- pool + LN(context): float4 loads, register-resident -------
        const int u    = bid - 512;
        const int wqc2 = u & 1, hq = (u >> 1) & 31, b = u >> 6;
        const int pp   = tid & 7;
        const int cg   = tid >> 3;
        const int ch0  = cg * 16;

        const float* Cb = context + ((size_t)b * CC + ch0) * 4096
                        + (size_t)(2 * hq) * 64 + (32 * wqc2 + 4 * pp);
        float pv0[16], pv1[16];
        float ss0 = 0.f, ss1 = 0.f, s20 = 0.f, s21 = 0.f;
        #pragma unroll
        for (int i = 0; i < 16; ++i) {
            const float4 r0 = *(const float4*)(Cb + (size_t)i * 4096);
            const float4 r1 = *(const float4*)(Cb + (size_t)i * 4096 + 64);
            const float v0 = (r0.x + r0.y + r1.x + r1.y) * 0.25f;
            const float v1 = (r0.z + r0.w + r1.z + r1.w) * 0.25f;
            pv0[i] = v0; pv1[i] = v1;
            ss0 += v0; s20 += v0 * v0;
            ss1 += v1; s21 += v1 * v1;
        }
        SsA[cg][2 * pp]     = ss0; S2A[cg][2 * pp]     = s20;
        SsA[cg][2 * pp + 1] = ss1; S2A[cg][2 * pp + 1] = s21;
        __syncthreads();
        if (tid < 16) {
            float ts = 0.f, t2 = 0.f;
            #pragma unroll
            for (int i = 0; i < 32; ++i) { ts += SsA[i][tid]; t2 += S2A[i][tid]; }
            const float mu  = ts * (1.f / CC);
            const float var = t2 * (1.f / CC) - mu * mu;
            Mu[tid] = mu; Rs[tid] = rsqrtf(var + 1e-5f);
        }
        __syncthreads();
        const float mu0 = Mu[2 * pp],     rs0 = Rs[2 * pp];
        const float mu1 = Mu[2 * pp + 1], rs1 = Rs[2 * pp + 1];
        const int pos0 = hq * 32 + wqc2 * 16 + 2 * pp;
        unsigned short* dst = (unsigned short*)cn
            + ((size_t)b * N_ + pos0) * CC + ch0;
        ushort8 a0, a1, b0, b1;
        #pragma unroll
        for (int i = 0; i < 8; ++i) {
            a0[i] = f2bf((pv0[i] - mu0) * rs0 * gc[ch0 + i] + betc[ch0 + i]);
            b0[i] = f2bf((pv1[i] - mu1) * rs1 * gc[ch0 + i] + betc[ch0 + i]);
        }
        #pragma unroll
        for (int i = 0; i < 8; ++i) {
            a1[i] = f2bf((pv0[8 + i] - mu0) * rs0 * gc[ch0 + 8 + i] + betc[ch0 + 8 + i]);
            b1[i] = f2bf((pv1[8 + i] - mu1) * rs1 * gc[ch0 + 8 + i] + betc[ch0 + 8 + i]);
        }
        *(ushort8*)(dst)          = a0;
        *(ushort8*)(dst + 8)      = a1;
        *(ushort8*)(dst + CC)     = b0;
        *(ushort8*)(dst + CC + 8) = b1;
    } else {
        // --------- LN(query) + raw bf16 copy: register-resident ---------
        const int u  = bid - 1024;
        const int nt = u & 15, b = u >> 4;
        const int nq = tid & 15;
        const int cg = tid >> 4;
        const int ch0 = cg * 16;
        const int nb  = nt * 64 + 4 * nq;

        const float* Qb = query + ((size_t)b * CQ + ch0) * N_ + nb;
        float qv[64];
        float ps[4] = {0.f, 0.f, 0.f, 0.f};
        float p2[4] = {0.f, 0.f, 0.f, 0.f};
        #pragma unroll
        for (int i = 0; i < 16; ++i) {
            const float4 v = *(const float4*)(Qb + (size_t)i * N_);
            qv[4 * i + 0] = v.x; qv[4 * i + 1] = v.y;
            qv[4 * i + 2] = v.z; qv[4 * i + 3] = v.w;
            ps[0] += v.x; p2[0] += v.x * v.x;
            ps[1] += v.y; p2[1] += v.y * v.y;
            ps[2] += v.z; p2[2] += v.z * v.z;
            ps[3] += v.w; p2[3] += v.w * v.w;
        }
        // raw bf16 residual copy (B,CQ,N), 8B per channel row
        #pragma unroll
        for (int i = 0; i < 16; ++i) {
            ushort4v o;
            o[0] = f2bf(qv[4 * i + 0]); o[1] = f2bf(qv[4 * i + 1]);
            o[2] = f2bf(qv[4 * i + 2]); o[3] = f2bf(qv[4 * i + 3]);
            *(ushort4v*)((unsigned short*)qraw + ((size_t)b * CQ + ch0 + i) * N_ + nb) = o;
        }
        #pragma unroll
        for (int j = 0; j < 4; ++j) {
            SsB[cg][4 * nq + j] = ps[j];
            S2B[cg][4 * nq + j] = p2[j];
        }
        __syncthreads();
        if (tid < 64) {
            float ts = 0.f, t2 = 0.f;
            #pragma unroll
            for (int i = 0; i < 16; ++i) { ts += SsB[i][tid]; t2 += S2B[i][tid]; }
            const float mu  = ts * (1.f / CQ);
            const float var = t2 * (1.f / CQ) - mu * mu;
            Mu[tid] = mu; Rs[tid] = rsqrtf(var + 1e-5f);
        }
        __syncthreads();
        #pragma unroll
        for (int j = 0; j < 4; ++j) {
            const float mu = Mu[4 * nq + j], rs = Rs[4 * nq + j];
            ushort8 o0, o1;
            #pragma unroll
            for (int i = 0; i < 8; ++i)
                o0[i] = f2bf((qv[4 * i + j] - mu) * rs * gq[ch0 + i] + betq[ch0 + i]);
            #pragma unroll
            for (int i = 0; i < 8; ++i)
                o1[i] = f2bf((qv[4 * (8 + i) + j] - mu) * rs * gq[ch0 + 8 + i] + betq[ch0 + 8 + i]);
            unsigned short* dst = (unsigned short*)qn
                + ((size_t)b * N_ + nb + j) * CQ + ch0;
            *(ushort8*)(dst)     = o0;
            *(ushort8*)(dst + 8) = o1;
        }
    }
}

// ---------------------------------------------------------------------------
// proj_all_k: 64n x 128co tiles (A re-read factor 2 instead of 4).
// 4 waves = 2(n) x 2(co); per wave 32n x 64co; staging is pure copy.
// V columns PERMUTED per 16-block. grid (16, 2, 16), block 256.
// ---------------------------------------------------------------------------
__global__ __launch_bounds__(256) void proj_all_k(
    const __hip_bfloat16* __restrict__ qn, const __hip_bfloat16* __restrict__ cn,
    const __hip_bfloat16* __restrict__ Wqt, const __hip_bfloat16* __restrict__ Wkt,
    const __hip_bfloat16* __restrict__ Wvt,
    const float* __restrict__ bq, const float* __restrict__ bk,
    const float* __restrict__ bv,
    __hip_bfloat16* __restrict__ Qb, __hip_bfloat16* __restrict__ Kb,
    __hip_bfloat16* __restrict__ Vt, float qsc) {
    __shared__ unsigned short As[64][40];
    __shared__ unsigned short B1[128][40];
    __shared__ unsigned short B2[128][40];

    const int zz = blockIdx.z;
    const int n0 = blockIdx.x * 64;
    const int c0 = blockIdx.y * 128;
    const int tid = threadIdx.x;
    const int wid = tid >> 6, lane = tid & 63;
    const int lg = lane >> 4, ln = lane & 15;
    const int wn0 = (wid & 1) * 32, wc0 = (wid >> 1) * 64;
    const int sr = tid >> 2;            // A staging row
    const int sk = (tid & 3) * 8;       // A staging col
    const int br = tid >> 1;            // B staging row 0..127
    const int bk0 = (tid & 1) * 16;     // B staging col base

    if (zz >= 8) {
        // ---------------- Q projection (K = 256) ----------------
        const int b = zz - 8;
        const unsigned short* Ab = (const unsigned short*)qn + ((size_t)b * N_ + n0) * CQ;
        const unsigned short* Wb = (const unsigned short*)Wqt + (size_t)c0 * CQ;
        f32x4 acc[2][4] = {};
        ushort8 ra  = *(const ushort8*)(Ab + (size_t)sr * CQ + sk);
        ushort8 rw0 = *(const ushort8*)(Wb + (size_t)br * CQ + bk0);
        ushort8 rw1 = *(const ushort8*)(Wb + (size_t)br * CQ + bk0 + 8);
        for (int t = 0; t < 8; ++t) {
            *(ushort8*)&As[sr][sk]      = ra;
            *(ushort8*)&B1[br][bk0]     = rw0;
            *(ushort8*)&B1[br][bk0 + 8] = rw1;
            __syncthreads();
            if (t < 7) {
                const int k0 = (t + 1) * 32;
                ra  = *(const ushort8*)(Ab + (size_t)sr * CQ + k0 + sk);
                rw0 = *(const ushort8*)(Wb + (size_t)br * CQ + k0 + bk0);
                rw1 = *(const ushort8*)(Wb + (size_t)br * CQ + k0 + bk0 + 8);
            }
            bf16x8 a[2], w[4];
            #pragma unroll
            for (int i = 0; i < 2; ++i) a[i] = ldb8(&As[wn0 + 16 * i + ln][8 * lg]);
            #pragma unroll
            for (int j = 0; j < 4; ++j) w[j] = ldb8(&B1[wc0 + 16 * j + ln][8 * lg]);
            #pragma unroll
            for (int i = 0; i < 2; ++i)
                #pragma unroll
                for (int j = 0; j < 4; ++j)
                    acc[i][j] = __builtin_amdgcn_mfma_f32_16x16x32_bf16(a[i], w[j], acc[i][j], 0, 0, 0);
            __syncthreads();
        }
        #pragma unroll
        for (int j = 0; j < 4; ++j) {
            const int co = c0 + wc0 + 16 * j + ln;
            const int h = co >> 5, d = co & 31;
            const float bb = bq[co];
            #pragma unroll
            for (int i = 0; i < 2; ++i)
                #pragma unroll
                for (int r = 0; r < 4; ++r) {
                    const int n = n0 + wn0 + 16 * i + 4 * lg + r;
                    Qb[(((size_t)b * NH + h) * N_ + n) * HD + d] =
                        __float2bfloat16((acc[i][j][r] + bb) * qsc);
                }
        }
    } else {
        // ---------------- K + V projection (K = 512) ----------------
        const int b = zz;
        const unsigned short* Ab  = (const unsigned short*)cn + ((size_t)b * N_ + n0) * CC;
        const unsigned short* Wkb = (const unsigned short*)Wkt + (size_t)c0 * CC;
        const unsigned short* Wvb = (const unsigned short*)Wvt + (size_t)c0 * CC;
        f32x4 accK[2][4] = {};
        f32x4 accV[2][4] = {};
        ushort8 ra  = *(const ushort8*)(Ab  + (size_t)sr * CC + sk);
        ushort8 rk0 = *(const ushort8*)(Wkb + (size_t)br * CC + bk0);
        ushort8 rk1 = *(const ushort8*)(Wkb + (size_t)br * CC + bk0 + 8);
        ushort8 rv0 = *(const ushort8*)(Wvb + (size_t)br * CC + bk0);
        ushort8 rv1 = *(const ushort8*)(Wvb + (size_t)br * CC + bk0 + 8);
        for (int t = 0; t < 16; ++t) {
            *(ushort8*)&As[sr][sk]      = ra;
            *(ushort8*)&B1[br][bk0]     = rk0;
            *(ushort8*)&B1[br][bk0 + 8] = rk1;
            *(ushort8*)&B2[br][bk0]     = rv0;
            *(ushort8*)&B2[br][bk0 + 8] = rv1;
            __syncthreads();
            if (t < 15) {
                const int k0 = (t + 1) * 32;
                ra  = *(const ushort8*)(Ab  + (size_t)sr * CC + k0 + sk);
                rk0 = *(const ushort8*)(Wkb + (size_t)br * CC + k0 + bk0);
                rk1 = *(const ushort8*)(Wkb + (size_t)br * CC + k0 + bk0 + 8);
                rv0 = *(const ushort8*)(Wvb + (size_t)br * CC + k0 + bk0);
                rv1 = *(const ushort8*)(Wvb + (size_t)br * CC + k0 + bk0 + 8);
            }
            bf16x8 a[2], wk[4], wv[4];
            #pragma unroll
            for (int i = 0; i < 2; ++i) a[i] = ldb8(&As[wn0 + 16 * i + ln][8 * lg]);
            #pragma unroll
            for (int j = 0; j < 4; ++j) {
                wk[j] = ldb8(&B1[wc0 + 16 * j + ln][8 * lg]);
                wv[j] = ldb8(&B2[wc0 + 16 * j + ln][8 * lg]);
            }
            #pragma unroll
            for (int i = 0; i < 2; ++i)
                #pragma unroll
                for (int j = 0; j < 4; ++j) {
                    accK[i][j] = __builtin_amdgcn_mfma_f32_16x16x32_bf16(a[i], wk[j], accK[i][j], 0, 0, 0);
                    accV[i][j] = __builtin_amdgcn_mfma_f32_16x16x32_bf16(a[i], wv[j], accV[i][j], 0, 0, 0);
                }
            __syncthreads();
        }
        #pragma unroll
        for (int j = 0; j < 4; ++j) {
            const int co = c0 + wc0 + 16 * j + ln;
            const int h = co >> 5, d = co & 31;
            const float bbk = bk[co], bbv = bv[co];
            #pragma unroll
            for (int i = 0; i < 2; ++i) {
                const int nb = n0 + wn0 + 16 * i + 4 * lg;
                #pragma unroll
                for (int r = 0; r < 4; ++r)
                    Kb[(((size_t)b * NH + h) * N_ + nb + r) * HD + d] =
                        __float2bfloat16(accK[i][j][r] + bbk);
                ushort4v o;
                #pragma unroll
                for (int r = 0; r < 4; ++r) o[r] = f2bf(accV[i][j][r] + bbv);
                const int g  = (nb >> 2) & 3;
                const int gp = ((g & 1) << 1) | (g >> 1);
                const int nbp = (nb & ~15) | (gp << 2);
                *(ushort4v*)((unsigned short*)Vt + (((size_t)b * NH + h) * HD + d) * N_ + nbp) = o;
            }
        }
    }
}

// ---------------------------------------------------------------------------
// 32x32 swapped-QK^T flash attention, in-register max-free softmax,
// 2-deep K prefetch + top-of-step V loads. grid (16, 64) XCD-swizzled.
// [R9-exact]
// ---------------------------------------------------------------------------
__global__ __launch_bounds__(256) void attn32_k(
    const __hip_bfloat16* __restrict__ Q,
    const __hip_bfloat16* __restrict__ K,
    const __hip_bfloat16* __restrict__ Vt,
    __hip_bfloat16* __restrict__ O) {
    __shared__ float accS[2][64][20];
    __shared__ float lwS[2][64];

    const int lin = blockIdx.x + 16 * blockIdx.y;
    const int eff = (lin & 7) * 128 + (lin >> 3);
    const int qt  = eff & 15;
    const int bh  = eff >> 4;
    const int b   = bh >> 3;
    const int h   = bh & 7;
    const int wid  = threadIdx.x >> 6;
    const int lane = threadIdx.x & 63;
    const int l31  = lane & 31;
    const int hh   = lane >> 5;
    const int qsub = wid >> 1;
    const int kvh  = wid & 1;
    const int q0   = qt * 64 + qsub * 32;

    const unsigned short* Qp = (const unsigned short*)Q + ((size_t)bh * N_ + q0) * HD;
    const unsigned short* Kbb = (const unsigned short*)K + (size_t)bh * N_ * HD;
    const unsigned short* Vb = (const unsigned short*)Vt + ((size_t)bh * HD + l31) * N_;

    bf16x8 qB[2];
    #pragma unroll
    for (int m = 0; m < 2; ++m)
        qB[m] = ldb8(Qp + (size_t)l31 * HD + 16 * m + 8 * hh);

    const f32x16 Z = {0.f,0.f,0.f,0.f,0.f,0.f,0.f,0.f,
                      0.f,0.f,0.f,0.f,0.f,0.f,0.f,0.f};
    f32x16 acc = Z;
    float ls0 = 0.f, ls1 = 0.f, ls2 = 0.f, ls3 = 0.f;

    const int kvbase = kvh * 512;
    const unsigned short* kp = Kbb + (size_t)(kvbase + l31) * HD + 8 * hh;
    const unsigned short* vp = Vb + kvbase + 8 * hh;

    bf16x8 kaA[2][4];
    #pragma unroll
    for (int j = 0; j < 4; ++j)
        kaA[0][j] = ldb8(kp + (j >> 1) * 1024 + (j & 1) * 16);

    #pragma unroll
    for (int st = 0; st < 8; ++st) {
        const int cur = st & 1;
        bf16x8 va[4];
        #pragma unroll
        for (int j = 0; j < 4; ++j)
            va[j] = ldb8(vp + st * 64 + 16 * j);
        if (st < 7) {
            const unsigned short* kp2 = kp + (size_t)(st + 1) * 2048;
            #pragma unroll
            for (int j = 0; j < 4; ++j)
                kaA[cur ^ 1][j] = ldb8(kp2 + (j >> 1) * 1024 + (j & 1) * 16);
        }

        f32x16 s0, s1;
        s0 = __builtin_amdgcn_mfma_f32_32x32x16_bf16(kaA[cur][0], qB[0], Z, 0, 0, 0);
        s0 = __builtin_amdgcn_mfma_f32_32x32x16_bf16(kaA[cur][1], qB[1], s0, 0, 0, 0);
        s1 = __builtin_amdgcn_mfma_f32_32x32x16_bf16(kaA[cur][2], qB[0], Z, 0, 0, 0);
        s1 = __builtin_amdgcn_mfma_f32_32x32x16_bf16(kaA[cur][3], qB[1], s1, 0, 0, 0);

        unsigned int pk[2][4][2];
        #pragma unroll
        for (int T = 0; T < 2; ++T) {
            float p[16];
            #pragma unroll
            for (int r = 0; r < 16; ++r)
                p[r] = __builtin_amdgcn_exp2f(T == 0 ? s0[r] : s1[r]);
            #pragma unroll
            for (int r = 0; r < 16; r += 4) {
                ls0 += p[r]; ls1 += p[r + 1]; ls2 += p[r + 2]; ls3 += p[r + 3];
            }
            #pragma unroll
            for (int c = 0; c < 4; ++c) {
                asm("v_cvt_pk_bf16_f32 %0, %1, %2"
                    : "=v"(pk[T][c][0]) : "v"(p[4 * c]), "v"(p[4 * c + 1]));
                asm("v_cvt_pk_bf16_f32 %0, %1, %2"
                    : "=v"(pk[T][c][1]) : "v"(p[4 * c + 2]), "v"(p[4 * c + 3]));
            }
        }

        #pragma unroll
        for (int w = 0; w < 4; ++w) {
            const int T = w >> 1, cp = w & 1;
            uint4v fu = {pk[T][2 * cp][0], pk[T][2 * cp][1],
                         pk[T][2 * cp + 1][0], pk[T][2 * cp + 1][1]};
            const bf16x8 pa = __builtin_bit_cast(bf16x8, fu);
            acc = __builtin_amdgcn_mfma_f32_32x32x16_bf16(pa, va[w], acc, 0, 0, 0);
        }
    }

    const float lsum = (ls0 + ls1) + (ls2 + ls3);
    const float lw = lsum + __shfl_xor(lsum, 32);

    if (kvh == 1) {
        #pragma unroll
        for (int r4 = 0; r4 < 4; ++r4) {
            float4 v = {acc[4 * r4], acc[4 * r4 + 1], acc[4 * r4 + 2], acc[4 * r4 + 3]};
            *(float4*)&accS[qsub][lane][4 * r4] = v;
        }
        lwS[qsub][lane] = lw;
    }
    __syncthreads();
    if (kvh == 0) {
        const float linv = 1.0f / (lw + lwS[qsub][lane]);
        #pragma unroll
        for (int r = 0; r < 16; ++r) {
            const int ql = (r & 3) + 8 * (r >> 2) + 4 * hh;
            const float vv = (acc[r] + accS[qsub][lane][r]) * __shfl(linv, ql);
            O[((size_t)b * N_ + q0 + ql) * CQ + h * HD + l31] = __float2bfloat16(vv);
        }
    }
}

// ---------------------------------------------------------------------------
// Output projection + bias + bf16 residual: 64n x 128co tiles.
// Ob (B,N,256) bf16 @ Wot + bo + qraw(bf16) -> out f32 (B,CQ,N).
// grid (16, 2, 8), block 256.
// ---------------------------------------------------------------------------
__global__ __launch_bounds__(256) void out_proj_k(const __hip_bfloat16* __restrict__ Ob,
                              const __hip_bfloat16* __restrict__ Wot,
                              const float* __restrict__ bo,
                              const __hip_bfloat16* __restrict__ qraw,
                              float* __restrict__ out) {
    __shared__ unsigned short As[64][40];
    __shared__ unsigned short B1[128][40];
    const int b  = blockIdx.z;
    const int n0 = blockIdx.x * 64;
    const int c0 = blockIdx.y * 128;
    const int tid = threadIdx.x;
    const int wid = tid >> 6, lane = tid & 63;
    const int lg = lane >> 4, ln = lane & 15;
    const int wn0 = (wid & 1) * 32, wc0 = (wid >> 1) * 64;
    const int sr = tid >> 2;
    const int sk = (tid & 3) * 8;
    const int br = tid >> 1;
    const int bk0 = (tid & 1) * 16;

    const unsigned short* Ab = (const unsigned short*)Ob + ((size_t)b * N_ + n0) * CQ;
    const unsigned short* Wb = (const unsigned short*)Wot + (size_t)c0 * CQ;

    f32x4 acc[2][4] = {};
    ushort8 ra  = *(const ushort8*)(Ab + (size_t)sr * CQ + sk);
    ushort8 rw0 = *(const ushort8*)(Wb + (size_t)br * CQ + bk0);
    ushort8 rw1 = *(const ushort8*)(Wb + (size_t)br * CQ + bk0 + 8);

    for (int t = 0; t < 8; ++t) {
        *(ushort8*)&As[sr][sk]      = ra;
        *(ushort8*)&B1[br][bk0]     = rw0;
        *(ushort8*)&B1[br][bk0 + 8] = rw1;
        __syncthreads();
        if (t < 7) {
            const int k0 = (t + 1) * 32;
            ra  = *(const ushort8*)(Ab + (size_t)sr * CQ + k0 + sk);
            rw0 = *(const ushort8*)(Wb + (size_t)br * CQ + k0 + bk0);
            rw1 = *(const ushort8*)(Wb + (size_t)br * CQ + k0 + bk0 + 8);
        }
        bf16x8 a[2], w[4];
        #pragma unroll
        for (int i = 0; i < 2; ++i)
            a[i] = ldb8(&As[wn0 + 16 * i + ln][8 * lg]);
        #pragma unroll
        for (int j = 0; j < 4; ++j)
            w[j] = ldb8(&B1[wc0 + 16 * j + ln][8 * lg]);
        #pragma unroll
        for (int i = 0; i < 2; ++i)
            #pragma unroll
            for (int j = 0; j < 4; ++j)
                acc[i][j] = __builtin_amdgcn_mfma_f32_16x16x32_bf16(a[i], w[j], acc[i][j], 0, 0, 0);
        __syncthreads();
    }

    #pragma unroll
    for (int j = 0; j < 4; ++j) {
        const int co = c0 + wc0 + 16 * j + ln;
        const float bb = bo[co];
        #pragma unroll
        for (int i = 0; i < 2; ++i) {
            const int nb = n0 + wn0 + 16 * i + 4 * lg;
            const ushort4v res = *(const ushort4v*)((const unsigned short*)qraw
                + ((size_t)b * CQ + co) * N_ + nb);
            float4 o;
            o.x = acc[i][j][0] + bb + bf2f(res[0]);
            o.y = acc[i][j][1] + bb + bf2f(res[1]);
            o.z = acc[i][j][2] + bb + bf2f(res[2]);
            o.w = acc[i][j][3] + bb + bf2f(res[3]);
            *(float4*)&out[((size_t)b * CQ + co) * N_ + nb] = o;
        }
    }
}

// ---------------------------------------------------------------------------
extern "C" void kernel_launch(void* const* d_in, const int* in_sizes, int n_in,
                              void* d_out, int out_size, void* d_ws, size_t ws_size,
                              hipStream_t stream) {
    const float* query   = (const float*)d_in[0];
    const float* context = (const float*)d_in[1];
    const float* Wq = (const float*)d_in[2];
    const float* bq = (const float*)d_in[3];
    const float* Wk = (const float*)d_in[4];
    const float* bk = (const float*)d_in[5];
    const float* Wv = (const float*)d_in[6];
    const float* bv = (const float*)d_in[7];
    const float* Wo = (const float*)d_in[8];
    const float* bo = (const float*)d_in[9];
    const float* gq   = (const float*)d_in[10];
    const float* betq = (const float*)d_in[11];
    const float* gc   = (const float*)d_in[12];
    const float* betc = (const float*)d_in[13];
    float* out = (float*)d_out;

    char* w = (char*)d_ws;
    __hip_bfloat16* qn   = (__hip_bfloat16*)w;  w += (size_t)B_ * N_ * CQ * 2;
    __hip_bfloat16* cn   = (__hip_bfloat16*)w;  w += (size_t)B_ * N_ * CC * 2;
    __hip_bfloat16* qraw = (__hip_bfloat16*)w;  w += (size_t)B_ * CQ * N_ * 2;
    __hip_bfloat16* Qb   = (__hip_bfloat16*)w;  w += (size_t)B_ * NH * N_ * HD * 2;
    __hip_bfloat16* Kb   = (__hip_bfloat16*)w;  w += (size_t)B_ * NH * N_ * HD * 2;
    __hip_bfloat16* Vt   = (__hip_bfloat16*)w;  w += (size_t)B_ * NH * HD * N_ * 2;
    __hip_bfloat16* Ob   = (__hip_bfloat16*)w;  w += (size_t)B_ * N_ * CQ * 2;
    __hip_bfloat16* Wqt  = (__hip_bfloat16*)w;  w += (size_t)CQ * CQ * 2;
    __hip_bfloat16* Wkt  = (__hip_bfloat16*)w;  w += (size_t)CQ * CC * 2;
    __hip_bfloat16* Wvt  = (__hip_bfloat16*)w;  w += (size_t)CQ * CC * 2;
    __hip_bfloat16* Wot  = (__hip_bfloat16*)w;  w += (size_t)CQ * CQ * 2;

    prep_k<<<dim3(1152), 256, 0, stream>>>(query, context, Wq, Wk, Wv, Wo,
                                           gq, betq, gc, betc,
                                           Wqt, Wkt, Wvt, Wot, qn, cn, qraw);

    // scale includes log2(e) so the softmax exp becomes a bare v_exp_f32
    const float qsc = 0.17677669529663687f * 1.4426950408889634f;
    proj_all_k<<<dim3(16, 2, 16), 256, 0, stream>>>(qn, cn, Wqt, Wkt, Wvt,
                                                    bq, bk, bv, Qb, Kb, Vt, qsc);

    attn32_k<<<dim3(16, 64), 256, 0, stream>>>(Qb, Kb, Vt, Ob);

    out_proj_k<<<dim3(16, 2, 8), 256, 0, stream>>>(Ob, Wot, bo, qraw, out);
}

// Round 15
// 67.100 us; speedup vs baseline: 1.0477x; 1.0187x over previous
//
#include <hip/hip_runtime.h>
#include <hip/hip_bf16.h>
#include <cstddef>

#define B_  8
#define CQ  256
#define CC  512
#define N_  1024   // Hq*Wq
#define HQ  32
#define WQ  32
#define NH  8
#define HD  32

typedef __bf16 bf16x8 __attribute__((ext_vector_type(8)));
typedef float f32x4 __attribute__((ext_vector_type(4)));
typedef float f32x16 __attribute__((ext_vector_type(16)));
typedef unsigned int uint4v __attribute__((ext_vector_type(4)));
typedef unsigned short ushort8 __attribute__((ext_vector_type(8)));
typedef unsigned short ushort4v __attribute__((ext_vector_type(4)));

__device__ __forceinline__ unsigned short f2bf(float x) {
    return __builtin_bit_cast(unsigned short, __float2bfloat16(x));
}
__device__ __forceinline__ float bf2f(unsigned short x) {
    return __bfloat162float(__builtin_bit_cast(__hip_bfloat16, x));
}
__device__ __forceinline__ bf16x8 ldb8(const unsigned short* p) {
    return __builtin_bit_cast(bf16x8, *(const ushort8*)p);
}

// ---------------------------------------------------------------------------
// prep_k (1152 blocks x 256): R9-exact except the query section ALSO stores
// qraw bf16 (B,Cq,N) for the bf16 residual read in out_proj.
//   [0,512):     weight transpose f32->bf16 (4 matrices)
//   [512,1024):  pool+LN(context) -> cn (B,N,Cc) bf16 [float4, 128B segments]
//   [1024,1152): LN(query) -> qn (B,N,Cq) bf16 + qraw bf16 (B,Cq,N)
// ---------------------------------------------------------------------------
__global__ __launch_bounds__(256) void prep_k(
    const float* __restrict__ query, const float* __restrict__ context,
    const float* __restrict__ Wq, const float* __restrict__ Wk,
    const float* __restrict__ Wv, const float* __restrict__ Wo,
    const float* __restrict__ gq, const float* __restrict__ betq,
    const float* __restrict__ gc, const float* __restrict__ betc,
    __hip_bfloat16* __restrict__ Wqt, __hip_bfloat16* __restrict__ Wkt,
    __hip_bfloat16* __restrict__ Wvt, __hip_bfloat16* __restrict__ Wot,
    __hip_bfloat16* __restrict__ qn, __hip_bfloat16* __restrict__ cn,
    __hip_bfloat16* __restrict__ qraw) {
    __shared__ float T[32][33];
    __shared__ float SsA[32][16];
    __shared__ float S2A[32][16];
    __shared__ float SsB[16][64];
    __shared__ float S2B[16][64];
    __shared__ float Mu[64], Rs[64];

    const int bid = blockIdx.x;
    const int tid = threadIdx.x;

    if (bid < 512) {
        // ---------------- weight transpose ----------------
        const int x = bid & 15, y = (bid >> 4) & 7, z = bid >> 7;
        const float* W; __hip_bfloat16* Wt; int K;
        switch (z) {
            case 0: W = Wq; Wt = Wqt; K = CQ; break;
            case 1: W = Wk; Wt = Wkt; K = CC; break;
            case 2: W = Wv; Wt = Wvt; K = CC; break;
            default: W = Wo; Wt = Wot; K = CQ; break;
        }
        const int k0 = x * 32;
        if (k0 >= K) return;
        const int c0 = y * 32;
        const int tx = tid & 31, ty = tid >> 5;
        #pragma unroll
        for (int i = 0; i < 4; ++i) {
            const int r = ty + 8 * i;
            T[r][tx] = W[(size_t)(k0 + r) * CQ + c0 + tx];
        }
        __syncthreads();
        #pragma unroll
        for (int i = 0; i < 4; ++i) {
            const int r = ty + 8 * i;
            Wt[(size_t)(c0 + r) * K + k0 + tx] = __float2bfloat16(T[tx][r]);
        }
    } else if (bid < 1024) {
        // ------- pool + LN(context): float4 loads, register-resident -------
        const int u    = bid - 512;
        const int wqc2 = u & 1, hq = (u >> 1) & 31, b = u >> 6;
        const int pp   = tid & 7;
        const int cg   = tid >> 3;
        const int ch0  = cg * 16;

        const float* Cb = context + ((size_t)b * CC + ch0) * 4096
                        + (size_t)(2 * hq) * 64 + (32 * wqc2 + 4 * pp);
        float pv0[16], pv1[16];
        float ss0 = 0.f, ss1 = 0.f, s20 = 0.f, s21 = 0.f;
        #pragma unroll
        for (int i = 0; i < 16; ++i) {
            const float4 r0 = *(const float4*)(Cb + (size_t)i * 4096);
            const float4 r1 = *(const float4*)(Cb + (size_t)i * 4096 + 64);
            const float v0 = (r0.x + r0.y + r1.x + r1.y) * 0.25f;
            const float v1 = (r0.z + r0.w + r1.z + r1.w) * 0.25f;
            pv0[i] = v0; pv1[i] = v1;
            ss0 += v0; s20 += v0 * v0;
            ss1 += v1; s21 += v1 * v1;
        }
        SsA[cg][2 * pp]     = ss0; S2A[cg][2 * pp]     = s20;
        SsA[cg][2 * pp + 1] = ss1; S2A[cg][2 * pp + 1] = s21;
        __syncthreads();
        if (tid < 16) {
            float ts = 0.f, t2 = 0.f;
            #pragma unroll
            for (int i = 0; i < 32; ++i) { ts += SsA[i][tid]; t2 += S2A[i][tid]; }
            const float mu  = ts * (1.f / CC);
            const float var = t2 * (1.f / CC) - mu * mu;
            Mu[tid] = mu; Rs[tid] = rsqrtf(var + 1e-5f);
        }
        __syncthreads();
        const float mu0 = Mu[2 * pp],     rs0 = Rs[2 * pp];
        const float mu1 = Mu[2 * pp + 1], rs1 = Rs[2 * pp + 1];
        const int pos0 = hq * 32 + wqc2 * 16 + 2 * pp;
        unsigned short* dst = (unsigned short*)cn
            + ((size_t)b * N_ + pos0) * CC + ch0;
        ushort8 a0, a1, b0, b1;
        #pragma unroll
        for (int i = 0; i < 8; ++i) {
            a0[i] = f2bf((pv0[i] - mu0) * rs0 * gc[ch0 + i] + betc[ch0 + i]);
            b0[i] = f2bf((pv1[i] - mu1) * rs1 * gc[ch0 + i] + betc[ch0 + i]);
        }
        #pragma unroll
        for (int i = 0; i < 8; ++i) {
            a1[i] = f2bf((pv0[8 + i] - mu0) * rs0 * gc[ch0 + 8 + i] + betc[ch0 + 8 + i]);
            b1[i] = f2bf((pv1[8 + i] - mu1) * rs1 * gc[ch0 + 8 + i] + betc[ch0 + 8 + i]);
        }
        *(ushort8*)(dst)          = a0;
        *(ushort8*)(dst + 8)      = a1;
        *(ushort8*)(dst + CC)     = b0;
        *(ushort8*)(dst + CC + 8) = b1;
    } else {
        // --------- LN(query) + qraw copy: float4 loads, register-resident ---------
        const int u  = bid - 1024;
        const int nt = u & 15, b = u >> 4;
        const int nq = tid & 15;
        const int cg = tid >> 4;
        const int ch0 = cg * 16;
        const int nb  = nt * 64 + 4 * nq;

        const float* Qb = query + ((size_t)b * CQ + ch0) * N_ + nb;
        float qv[64];
        float ps[4] = {0.f, 0.f, 0.f, 0.f};
        float p2[4] = {0.f, 0.f, 0.f, 0.f};
        #pragma unroll
        for (int i = 0; i < 16; ++i) {
            const float4 v = *(const float4*)(Qb + (size_t)i * N_);
            qv[4 * i + 0] = v.x; qv[4 * i + 1] = v.y;
            qv[4 * i + 2] = v.z; qv[4 * i + 3] = v.w;
            ps[0] += v.x; p2[0] += v.x * v.x;
            ps[1] += v.y; p2[1] += v.y * v.y;
            ps[2] += v.z; p2[2] += v.z * v.z;
            ps[3] += v.w; p2[3] += v.w * v.w;
        }
        // raw bf16 residual copy (B,Cq,N), 8B per channel row
        #pragma unroll
        for (int i = 0; i < 16; ++i) {
            ushort4v o;
            o[0] = f2bf(qv[4 * i + 0]); o[1] = f2bf(qv[4 * i + 1]);
            o[2] = f2bf(qv[4 * i + 2]); o[3] = f2bf(qv[4 * i + 3]);
            *(ushort4v*)((unsigned short*)qraw + ((size_t)b * CQ + ch0 + i) * N_ + nb) = o;
        }
        #pragma unroll
        for (int j = 0; j < 4; ++j) {
            SsB[cg][4 * nq + j] = ps[j];
            S2B[cg][4 * nq + j] = p2[j];
        }
        __syncthreads();
        if (tid < 64) {
            float ts = 0.f, t2 = 0.f;
            #pragma unroll
            for (int i = 0; i < 16; ++i) { ts += SsB[i][tid]; t2 += S2B[i][tid]; }
            const float mu  = ts * (1.f / CQ);
            const float var = t2 * (1.f / CQ) - mu * mu;
            Mu[tid] = mu; Rs[tid] = rsqrtf(var + 1e-5f);
        }
        __syncthreads();
        #pragma unroll
        for (int j = 0; j < 4; ++j) {
            const float mu = Mu[4 * nq + j], rs = Rs[4 * nq + j];
            ushort8 o0, o1;
            #pragma unroll
            for (int i = 0; i < 8; ++i)
                o0[i] = f2bf((qv[4 * i + j] - mu) * rs * gq[ch0 + i] + betq[ch0 + i]);
            #pragma unroll
            for (int i = 0; i < 8; ++i)
                o1[i] = f2bf((qv[4 * (8 + i) + j] - mu) * rs * gq[ch0 + 8 + i] + betq[ch0 + 8 + i]);
            unsigned short* dst = (unsigned short*)qn
                + ((size_t)b * N_ + nb + j) * CQ + ch0;
            *(ushort8*)(dst)     = o0;
            *(ushort8*)(dst + 8) = o1;
        }
    }
}

// ---------------------------------------------------------------------------
// proj_all_k: Q projection (z>=8) and fused K+V projection (z<8) in one
// launch, reg-staged global prefetch. V columns written PERMUTED per
// 16-block (groups-of-4 1<->2 swap) so attention reads contiguous PV B-frags.
// grid (16, 4, 16), block 256.  [R9-exact]
// ---------------------------------------------------------------------------
__global__ __launch_bounds__(256) void proj_all_k(
    const __hip_bfloat16* __restrict__ qn, const __hip_bfloat16* __restrict__ cn,
    const __hip_bfloat16* __restrict__ Wqt, const __hip_bfloat16* __restrict__ Wkt,
    const __hip_bfloat16* __restrict__ Wvt,
    const float* __restrict__ bq, const float* __restrict__ bk,
    const float* __restrict__ bv,
    __hip_bfloat16* __restrict__ Qb, __hip_bfloat16* __restrict__ Kb,
    __hip_bfloat16* __restrict__ Vt, float qsc) {
    __shared__ unsigned short As[64][40];
    __shared__ unsigned short B1[64][40];
    __shared__ unsigned short B2[64][40];

    const int zz = blockIdx.z;
    const int n0 = blockIdx.x * 64;
    const int c0 = blockIdx.y * 64;
    const int tid = threadIdx.x;
    const int wid = tid >> 6, lane = tid & 63;
    const int lg = lane >> 4, ln = lane & 15;
    const int wn0 = (wid & 1) * 32, wc0 = (wid >> 1) * 32;
    const int sr = tid >> 2;
    const int sk = (tid & 3) * 8;

    if (zz >= 8) {
        // ---------------- Q projection (K = 256) ----------------
        const int b = zz - 8;
        const unsigned short* Ab = (const unsigned short*)qn + ((size_t)b * N_ + n0) * CQ;
        const unsigned short* Wb = (const unsigned short*)Wqt + (size_t)c0 * CQ;
        f32x4 acc[2][2] = {};
        ushort8 ra = *(const ushort8*)(Ab + (size_t)sr * CQ + sk);
        ushort8 rw = *(const ushort8*)(Wb + (size_t)sr * CQ + sk);
        for (int t = 0; t < 8; ++t) {
            *(ushort8*)&As[sr][sk] = ra;
            *(ushort8*)&B1[sr][sk] = rw;
            __syncthreads();
            if (t < 7) {
                ra = *(const ushort8*)(Ab + (size_t)sr * CQ + (t + 1) * 32 + sk);
                rw = *(const ushort8*)(Wb + (size_t)sr * CQ + (t + 1) * 32 + sk);
            }
            bf16x8 a[2], w[2];
            #pragma unroll
            for (int i = 0; i < 2; ++i) a[i] = ldb8(&As[wn0 + 16 * i + ln][8 * lg]);
            #pragma unroll
            for (int j = 0; j < 2; ++j) w[j] = ldb8(&B1[wc0 + 16 * j + ln][8 * lg]);
            #pragma unroll
            for (int i = 0; i < 2; ++i)
                #pragma unroll
                for (int j = 0; j < 2; ++j)
                    acc[i][j] = __builtin_amdgcn_mfma_f32_16x16x32_bf16(a[i], w[j], acc[i][j], 0, 0, 0);
            __syncthreads();
        }
        #pragma unroll
        for (int j = 0; j < 2; ++j) {
            const int co = c0 + wc0 + 16 * j + ln;
            const int h = co >> 5, d = co & 31;
            const float bb = bq[co];
            #pragma unroll
            for (int i = 0; i < 2; ++i)
                #pragma unroll
                for (int r = 0; r < 4; ++r) {
                    const int n = n0 + wn0 + 16 * i + 4 * lg + r;
                    Qb[(((size_t)b * NH + h) * N_ + n) * HD + d] =
                        __float2bfloat16((acc[i][j][r] + bb) * qsc);
                }
        }
    } else {
        // ---------------- K + V projection (K = 512) ----------------
        const int b = zz;
        const unsigned short* Ab  = (const unsigned short*)cn + ((size_t)b * N_ + n0) * CC;
        const unsigned short* Wkb = (const unsigned short*)Wkt + (size_t)c0 * CC;
        const unsigned short* Wvb = (const unsigned short*)Wvt + (size_t)c0 * CC;
        f32x4 accK[2][2] = {};
        f32x4 accV[2][2] = {};
        ushort8 ra = *(const ushort8*)(Ab  + (size_t)sr * CC + sk);
        ushort8 rk = *(const ushort8*)(Wkb + (size_t)sr * CC + sk);
        ushort8 rv = *(const ushort8*)(Wvb + (size_t)sr * CC + sk);
        for (int t = 0; t < 16; ++t) {
            *(ushort8*)&As[sr][sk] = ra;
            *(ushort8*)&B1[sr][sk] = rk;
            *(ushort8*)&B2[sr][sk] = rv;
            __syncthreads();
            if (t < 15) {
                ra = *(const ushort8*)(Ab  + (size_t)sr * CC + (t + 1) * 32 + sk);
                rk = *(const ushort8*)(Wkb + (size_t)sr * CC + (t + 1) * 32 + sk);
                rv = *(const ushort8*)(Wvb + (size_t)sr * CC + (t + 1) * 32 + sk);
            }
            bf16x8 a[2], wk[2], wv[2];
            #pragma unroll
            for (int i = 0; i < 2; ++i) {
                a[i]  = ldb8(&As[wn0 + 16 * i + ln][8 * lg]);
                wk[i] = ldb8(&B1[wc0 + 16 * i + ln][8 * lg]);
                wv[i] = ldb8(&B2[wc0 + 16 * i + ln][8 * lg]);
            }
            #pragma unroll
            for (int i = 0; i < 2; ++i)
                #pragma unroll
                for (int j = 0; j < 2; ++j) {
                    accK[i][j] = __builtin_amdgcn_mfma_f32_16x16x32_bf16(a[i], wk[j], accK[i][j], 0, 0, 0);
                    accV[i][j] = __builtin_amdgcn_mfma_f32_16x16x32_bf16(a[i], wv[j], accV[i][j], 0, 0, 0);
                }
            __syncthreads();
        }
        #pragma unroll
        for (int j = 0; j < 2; ++j) {
            const int co = c0 + wc0 + 16 * j + ln;
            const int h = co >> 5, d = co & 31;
            const float bbk = bk[co], bbv = bv[co];
            #pragma unroll
            for (int i = 0; i < 2; ++i) {
                const int nb = n0 + wn0 + 16 * i + 4 * lg;
                #pragma unroll
                for (int r = 0; r < 4; ++r)
                    Kb[(((size_t)b * NH + h) * N_ + nb + r) * HD + d] =
                        __float2bfloat16(accK[i][j][r] + bbk);
                ushort4v o;
                #pragma unroll
                for (int r = 0; r < 4; ++r) o[r] = f2bf(accV[i][j][r] + bbv);
                const int g  = (nb >> 2) & 3;
                const int gp = ((g & 1) << 1) | (g >> 1);
                const int nbp = (nb & ~15) | (gp << 2);
                *(ushort4v*)((unsigned short*)Vt + (((size_t)b * NH + h) * HD + d) * N_ + nbp) = o;
            }
        }
    }
}

// ---------------------------------------------------------------------------
// 32x32 swapped-QK^T flash attention, in-register max-free softmax,
// 2-deep K prefetch + top-of-step V loads. grid (16, 64) XCD-swizzled.
// [R9-exact]
// ---------------------------------------------------------------------------
__global__ __launch_bounds__(256) void attn32_k(
    const __hip_bfloat16* __restrict__ Q,
    const __hip_bfloat16* __restrict__ K,
    const __hip_bfloat16* __restrict__ Vt,
    __hip_bfloat16* __restrict__ O) {
    __shared__ float accS[2][64][20];
    __shared__ float lwS[2][64];

    const int lin = blockIdx.x + 16 * blockIdx.y;
    const int eff = (lin & 7) * 128 + (lin >> 3);
    const int qt  = eff & 15;
    const int bh  = eff >> 4;
    const int b   = bh >> 3;
    const int h   = bh & 7;
    const int wid  = threadIdx.x >> 6;
    const int lane = threadIdx.x & 63;
    const int l31  = lane & 31;
    const int hh   = lane >> 5;
    const int qsub = wid >> 1;
    const int kvh  = wid & 1;
    const int q0   = qt * 64 + qsub * 32;

    const unsigned short* Qp = (const unsigned short*)Q + ((size_t)bh * N_ + q0) * HD;
    const unsigned short* Kbb = (const unsigned short*)K + (size_t)bh * N_ * HD;
    const unsigned short* Vb = (const unsigned short*)Vt + ((size_t)bh * HD + l31) * N_;

    bf16x8 qB[2];
    #pragma unroll
    for (int m = 0; m < 2; ++m)
        qB[m] = ldb8(Qp + (size_t)l31 * HD + 16 * m + 8 * hh);

    const f32x16 Z = {0.f,0.f,0.f,0.f,0.f,0.f,0.f,0.f,
                      0.f,0.f,0.f,0.f,0.f,0.f,0.f,0.f};
    f32x16 acc = Z;
    float ls0 = 0.f, ls1 = 0.f, ls2 = 0.f, ls3 = 0.f;

    const int kvbase = kvh * 512;
    const unsigned short* kp = Kbb + (size_t)(kvbase + l31) * HD + 8 * hh;
    const unsigned short* vp = Vb + kvbase + 8 * hh;

    bf16x8 kaA[2][4];
    #pragma unroll
    for (int j = 0; j < 4; ++j)
        kaA[0][j] = ldb8(kp + (j >> 1) * 1024 + (j & 1) * 16);

    #pragma unroll
    for (int st = 0; st < 8; ++st) {
        const int cur = st & 1;
        bf16x8 va[4];
        #pragma unroll
        for (int j = 0; j < 4; ++j)
            va[j] = ldb8(vp + st * 64 + 16 * j);
        if (st < 7) {
            const unsigned short* kp2 = kp + (size_t)(st + 1) * 2048;
            #pragma unroll
            for (int j = 0; j < 4; ++j)
                kaA[cur ^ 1][j] = ldb8(kp2 + (j >> 1) * 1024 + (j & 1) * 16);
        }

        f32x16 s0, s1;
        s0 = __builtin_amdgcn_mfma_f32_32x32x16_bf16(kaA[cur][0], qB[0], Z, 0, 0, 0);
        s0 = __builtin_amdgcn_mfma_f32_32x32x16_bf16(kaA[cur][1], qB[1], s0, 0, 0, 0);
        s1 = __builtin_amdgcn_mfma_f32_32x32x16_bf16(kaA[cur][2], qB[0], Z, 0, 0, 0);
        s1 = __builtin_amdgcn_mfma_f32_32x32x16_bf16(kaA[cur][3], qB[1], s1, 0, 0, 0);

        unsigned int pk[2][4][2];
        #pragma unroll
        for (int T = 0; T < 2; ++T) {
            float p[16];
            #pragma unroll
            for (int r = 0; r < 16; ++r)
                p[r] = __builtin_amdgcn_exp2f(T == 0 ? s0[r] : s1[r]);
            #pragma unroll
            for (int r = 0; r < 16; r += 4) {
                ls0 += p[r]; ls1 += p[r + 1]; ls2 += p[r + 2]; ls3 += p[r + 3];
            }
            #pragma unroll
            for (int c = 0; c < 4; ++c) {
                asm("v_cvt_pk_bf16_f32 %0, %1, %2"
                    : "=v"(pk[T][c][0]) : "v"(p[4 * c]), "v"(p[4 * c + 1]));
                asm("v_cvt_pk_bf16_f32 %0, %1, %2"
                    : "=v"(pk[T][c][1]) : "v"(p[4 * c + 2]), "v"(p[4 * c + 3]));
            }
        }

        #pragma unroll
        for (int w = 0; w < 4; ++w) {
            const int T = w >> 1, cp = w & 1;
            uint4v fu = {pk[T][2 * cp][0], pk[T][2 * cp][1],
                         pk[T][2 * cp + 1][0], pk[T][2 * cp + 1][1]};
            const bf16x8 pa = __builtin_bit_cast(bf16x8, fu);
            acc = __builtin_amdgcn_mfma_f32_32x32x16_bf16(pa, va[w], acc, 0, 0, 0);
        }
    }

    const float lsum = (ls0 + ls1) + (ls2 + ls3);
    const float lw = lsum + __shfl_xor(lsum, 32);

    if (kvh == 1) {
        #pragma unroll
        for (int r4 = 0; r4 < 4; ++r4) {
            float4 v = {acc[4 * r4], acc[4 * r4 + 1], acc[4 * r4 + 2], acc[4 * r4 + 3]};
            *(float4*)&accS[qsub][lane][4 * r4] = v;
        }
        lwS[qsub][lane] = lw;
    }
    __syncthreads();
    if (kvh == 0) {
        const float linv = 1.0f / (lw + lwS[qsub][lane]);
        #pragma unroll
        for (int r = 0; r < 16; ++r) {
            const int ql = (r & 3) + 8 * (r >> 2) + 4 * hh;
            const float vv = (acc[r] + accS[qsub][lane][r]) * __shfl(linv, ql);
            O[((size_t)b * N_ + q0 + ql) * CQ + h * HD + l31] = __float2bfloat16(vv);
        }
    }
}

// ---------------------------------------------------------------------------
// Output projection + bias + bf16 residual, reg-staged prefetch.
// grid (16, 4, B), block 256.  [R9-exact except qraw residual]
// ---------------------------------------------------------------------------
__global__ __launch_bounds__(256) void out_proj_k(const __hip_bfloat16* __restrict__ Ob,
                              const __hip_bfloat16* __restrict__ Wot,
                              const float* __restrict__ bo,
                              const __hip_bfloat16* __restrict__ qraw,
                              float* __restrict__ out) {
    __shared__ unsigned short As[64][40];
    __shared__ unsigned short Bs[64][40];
    const int b  = blockIdx.z;
    const int n0 = blockIdx.x * 64;
    const int c0 = blockIdx.y * 64;
    const int tid = threadIdx.x;
    const int wid = tid >> 6, lane = tid & 63;
    const int lg = lane >> 4, ln = lane & 15;
    const int wn0 = (wid & 1) * 32, wc0 = (wid >> 1) * 32;

    const unsigned short* Ab = (const unsigned short*)Ob + ((size_t)b * N_ + n0) * CQ;
    const unsigned short* Wb = (const unsigned short*)Wot + (size_t)c0 * CQ;
    const int sr = tid >> 2;
    const int sk = (tid & 3) * 8;

    f32x4 acc[2][2] = {};
    ushort8 ra = *(const ushort8*)(Ab + (size_t)sr * CQ + sk);
    ushort8 rw = *(const ushort8*)(Wb + (size_t)sr * CQ + sk);

    for (int t = 0; t < 8; ++t) {
        *(ushort8*)&As[sr][sk] = ra;
        *(ushort8*)&Bs[sr][sk] = rw;
        __syncthreads();
        if (t < 7) {
            ra = *(const ushort8*)(Ab + (size_t)sr * CQ + (t + 1) * 32 + sk);
            rw = *(const ushort8*)(Wb + (size_t)sr * CQ + (t + 1) * 32 + sk);
        }
        bf16x8 a[2], w[2];
        #pragma unroll
        for (int i = 0; i < 2; ++i)
            a[i] = ldb8(&As[wn0 + 16 * i + ln][8 * lg]);
        #pragma unroll
        for (int j = 0; j < 2; ++j)
            w[j] = ldb8(&Bs[wc0 + 16 * j + ln][8 * lg]);
        #pragma unroll
        for (int i = 0; i < 2; ++i)
            #pragma unroll
            for (int j = 0; j < 2; ++j)
                acc[i][j] = __builtin_amdgcn_mfma_f32_16x16x32_bf16(a[i], w[j], acc[i][j], 0, 0, 0);
        __syncthreads();
    }

    #pragma unroll
    for (int j = 0; j < 2; ++j) {
        const int co = c0 + wc0 + 16 * j + ln;
        const float bb = bo[co];
        #pragma unroll
        for (int i = 0; i < 2; ++i) {
            const int nb = n0 + wn0 + 16 * i + 4 * lg;
            const ushort4v res = *(const ushort4v*)((const unsigned short*)qraw
                + ((size_t)b * CQ + co) * N_ + nb);
            float4 o;
            o.x = acc[i][j][0] + bb + bf2f(res[0]);
            o.y = acc[i][j][1] + bb + bf2f(res[1]);
            o.z = acc[i][j][2] + bb + bf2f(res[2]);
            o.w = acc[i][j][3] + bb + bf2f(res[3]);
            *(float4*)&out[((size_t)b * CQ + co) * N_ + nb] = o;
        }
    }
}

// ---------------------------------------------------------------------------
extern "C" void kernel_launch(void* const* d_in, const int* in_sizes, int n_in,
                              void* d_out, int out_size, void* d_ws, size_t ws_size,
                              hipStream_t stream) {
    const float* query   = (const float*)d_in[0];
    const float* context = (const float*)d_in[1];
    const float* Wq = (const float*)d_in[2];
    const float* bq = (const float*)d_in[3];
    const float* Wk = (const float*)d_in[4];
    const float* bk = (const float*)d_in[5];
    const float* Wv = (const float*)d_in[6];
    const float* bv = (const float*)d_in[7];
    const float* Wo = (const float*)d_in[8];
    const float* bo = (const float*)d_in[9];
    const float* gq   = (const float*)d_in[10];
    const float* betq = (const float*)d_in[11];
    const float* gc   = (const float*)d_in[12];
    const float* betc = (const float*)d_in[13];
    float* out = (float*)d_out;

    char* w = (char*)d_ws;
    __hip_bfloat16* qn   = (__hip_bfloat16*)w;  w += (size_t)B_ * N_ * CQ * 2;
    __hip_bfloat16* cn   = (__hip_bfloat16*)w;  w += (size_t)B_ * N_ * CC * 2;
    __hip_bfloat16* qraw = (__hip_bfloat16*)w;  w += (size_t)B_ * CQ * N_ * 2;
    __hip_bfloat16* Qb   = (__hip_bfloat16*)w;  w += (size_t)B_ * NH * N_ * HD * 2;
    __hip_bfloat16* Kb   = (__hip_bfloat16*)w;  w += (size_t)B_ * NH * N_ * HD * 2;
    __hip_bfloat16* Vt   = (__hip_bfloat16*)w;  w += (size_t)B_ * NH * HD * N_ * 2;
    __hip_bfloat16* Ob   = (__hip_bfloat16*)w;  w += (size_t)B_ * N_ * CQ * 2;
    __hip_bfloat16* Wqt  = (__hip_bfloat16*)w;  w += (size_t)CQ * CQ * 2;
    __hip_bfloat16* Wkt  = (__hip_bfloat16*)w;  w += (size_t)CQ * CC * 2;
    __hip_bfloat16* Wvt  = (__hip_bfloat16*)w;  w += (size_t)CQ * CC * 2;
    __hip_bfloat16* Wot  = (__hip_bfloat16*)w;  w += (size_t)CQ * CQ * 2;

    prep_k<<<dim3(1152), 256, 0, stream>>>(query, context, Wq, Wk, Wv, Wo,
                                           gq, betq, gc, betc,
                                           Wqt, Wkt, Wvt, Wot, qn, cn, qraw);

    // scale includes log2(e) so the softmax exp becomes a bare v_exp_f32
    const float qsc = 0.17677669529663687f * 1.4426950408889634f;
    proj_all_k<<<dim3(16, 4, 16), 256, 0, stream>>>(qn, cn, Wqt, Wkt, Wvt,
                                                    bq, bk, bv, Qb, Kb, Vt, qsc);

    attn32_k<<<dim3(16, 64), 256, 0, stream>>>(Qb, Kb, Vt, Ob);

    out_proj_k<<<dim3(16, 4, 8), 256, 0, stream>>>(Ob, Wot, bo, qraw, out);
}

// Round 16
// 66.619 us; speedup vs baseline: 1.0553x; 1.0072x over previous
//
#include <hip/hip_runtime.h>
#include <hip/hip_bf16.h>
#include <cstddef>

#define B_  8
#define CQ  256
#define CC  512
#define N_  1024   // Hq*Wq
#define HQ  32
#define WQ  32
#define NH  8
#define HD  32

typedef __bf16 bf16x8 __attribute__((ext_vector_type(8)));
typedef float f32x4 __attribute__((ext_vector_type(4)));
typedef float f32x16 __attribute__((ext_vector_type(16)));
typedef unsigned int uint4v __attribute__((ext_vector_type(4)));
typedef unsigned short ushort8 __attribute__((ext_vector_type(8)));
typedef unsigned short ushort4v __attribute__((ext_vector_type(4)));

__device__ __forceinline__ unsigned short f2bf(float x) {
    return __builtin_bit_cast(unsigned short, __float2bfloat16(x));
}
__device__ __forceinline__ float bf2f(unsigned short x) {
    return __bfloat162float(__builtin_bit_cast(__hip_bfloat16, x));
}
__device__ __forceinline__ bf16x8 ldb8(const unsigned short* p) {
    return __builtin_bit_cast(bf16x8, *(const ushort8*)p);
}

// ---------------------------------------------------------------------------
// prep_k (1280 blocks x 256), dispatch-ordered long-pole-first:
//   [0,256):    LN(query) -> qn bf16 + qraw bf16. 256 blocks (was 128): each
//               32 positions x 256 ch; 8-load chains; 128B segments kept.
//   [256,768):  pool+LN(context) -> cn bf16 [R9-exact layout]
//   [768,1280): weight transpose f32->bf16 (tiny blocks, fill the tail)
// ---------------------------------------------------------------------------
__global__ __launch_bounds__(256) void prep_k(
    const float* __restrict__ query, const float* __restrict__ context,
    const float* __restrict__ Wq, const float* __restrict__ Wk,
    const float* __restrict__ Wv, const float* __restrict__ Wo,
    const float* __restrict__ gq, const float* __restrict__ betq,
    const float* __restrict__ gc, const float* __restrict__ betc,
    __hip_bfloat16* __restrict__ Wqt, __hip_bfloat16* __restrict__ Wkt,
    __hip_bfloat16* __restrict__ Wvt, __hip_bfloat16* __restrict__ Wot,
    __hip_bfloat16* __restrict__ qn, __hip_bfloat16* __restrict__ cn,
    __hip_bfloat16* __restrict__ qraw) {
    __shared__ float T[32][33];
    __shared__ float SsA[32][16];
    __shared__ float S2A[32][16];
    __shared__ float SsB[32][32];
    __shared__ float S2B[32][32];
    __shared__ float Mu[32], Rs[32];

    const int bid = blockIdx.x;
    const int tid = threadIdx.x;

    if (bid < 256) {
        // --------- LN(query) + qraw: 256 blocks, 32 positions each ---------
        const int nt = bid & 31, b = bid >> 5;
        const int nq = tid & 7;           // n-quad: positions 4nq..4nq+3 (of 32)
        const int cg = tid >> 3;          // channel group 0..31 (8 ch each)
        const int ch0 = cg * 8;
        const int nb  = nt * 32 + 4 * nq;

        const float* Qb = query + ((size_t)b * CQ + ch0) * N_ + nb;
        float qv[32];                     // [8 ch][4 pos]
        float ps[4] = {0.f, 0.f, 0.f, 0.f};
        float p2[4] = {0.f, 0.f, 0.f, 0.f};
        #pragma unroll
        for (int i = 0; i < 8; ++i) {
            const float4 v = *(const float4*)(Qb + (size_t)i * N_);
            qv[4 * i + 0] = v.x; qv[4 * i + 1] = v.y;
            qv[4 * i + 2] = v.z; qv[4 * i + 3] = v.w;
            ps[0] += v.x; p2[0] += v.x * v.x;
            ps[1] += v.y; p2[1] += v.y * v.y;
            ps[2] += v.z; p2[2] += v.z * v.z;
            ps[3] += v.w; p2[3] += v.w * v.w;
        }
        // raw bf16 residual copy (B,Cq,N), 8B per channel row
        #pragma unroll
        for (int i = 0; i < 8; ++i) {
            ushort4v o;
            o[0] = f2bf(qv[4 * i + 0]); o[1] = f2bf(qv[4 * i + 1]);
            o[2] = f2bf(qv[4 * i + 2]); o[3] = f2bf(qv[4 * i + 3]);
            *(ushort4v*)((unsigned short*)qraw + ((size_t)b * CQ + ch0 + i) * N_ + nb) = o;
        }
        #pragma unroll
        for (int j = 0; j < 4; ++j) {
            SsB[cg][4 * nq + j] = ps[j];
            S2B[cg][4 * nq + j] = p2[j];
        }
        __syncthreads();
        if (tid < 32) {
            float ts = 0.f, t2 = 0.f;
            #pragma unroll
            for (int i = 0; i < 32; ++i) { ts += SsB[i][tid]; t2 += S2B[i][tid]; }
            const float mu  = ts * (1.f / CQ);
            const float var = t2 * (1.f / CQ) - mu * mu;
            Mu[tid] = mu; Rs[tid] = rsqrtf(var + 1e-5f);
        }
        __syncthreads();
        #pragma unroll
        for (int j = 0; j < 4; ++j) {
            const float mu = Mu[4 * nq + j], rs = Rs[4 * nq + j];
            ushort8 o;
            #pragma unroll
            for (int i = 0; i < 8; ++i)
                o[i] = f2bf((qv[4 * i + j] - mu) * rs * gq[ch0 + i] + betq[ch0 + i]);
            *(ushort8*)((unsigned short*)qn + ((size_t)b * N_ + nb + j) * CQ + ch0) = o;
        }
    } else if (bid < 768) {
        // ------- pool + LN(context): float4 loads, register-resident -------
        const int u    = bid - 256;
        const int wqc2 = u & 1, hq = (u >> 1) & 31, b = u >> 6;
        const int pp   = tid & 7;
        const int cg   = tid >> 3;
        const int ch0  = cg * 16;

        const float* Cb = context + ((size_t)b * CC + ch0) * 4096
                        + (size_t)(2 * hq) * 64 + (32 * wqc2 + 4 * pp);
        float pv0[16], pv1[16];
        float ss0 = 0.f, ss1 = 0.f, s20 = 0.f, s21 = 0.f;
        #pragma unroll
        for (int i = 0; i < 16; ++i) {
            const float4 r0 = *(const float4*)(Cb + (size_t)i * 4096);
            const float4 r1 = *(const float4*)(Cb + (size_t)i * 4096 + 64);
            const float v0 = (r0.x + r0.y + r1.x + r1.y) * 0.25f;
            const float v1 = (r0.z + r0.w + r1.z + r1.w) * 0.25f;
            pv0[i] = v0; pv1[i] = v1;
            ss0 += v0; s20 += v0 * v0;
            ss1 += v1; s21 += v1 * v1;
        }
        SsA[cg][2 * pp]     = ss0; S2A[cg][2 * pp]     = s20;
        SsA[cg][2 * pp + 1] = ss1; S2A[cg][2 * pp + 1] = s21;
        __syncthreads();
        if (tid < 16) {
            float ts = 0.f, t2 = 0.f;
            #pragma unroll
            for (int i = 0; i < 32; ++i) { ts += SsA[i][tid]; t2 += S2A[i][tid]; }
            const float mu  = ts * (1.f / CC);
            const float var = t2 * (1.f / CC) - mu * mu;
            Mu[tid] = mu; Rs[tid] = rsqrtf(var + 1e-5f);
        }
        __syncthreads();
        const float mu0 = Mu[2 * pp],     rs0 = Rs[2 * pp];
        const float mu1 = Mu[2 * pp + 1], rs1 = Rs[2 * pp + 1];
        const int pos0 = hq * 32 + wqc2 * 16 + 2 * pp;
        unsigned short* dst = (unsigned short*)cn
            + ((size_t)b * N_ + pos0) * CC + ch0;
        ushort8 a0, a1, b0, b1;
        #pragma unroll
        for (int i = 0; i < 8; ++i) {
            a0[i] = f2bf((pv0[i] - mu0) * rs0 * gc[ch0 + i] + betc[ch0 + i]);
            b0[i] = f2bf((pv1[i] - mu1) * rs1 * gc[ch0 + i] + betc[ch0 + i]);
        }
        #pragma unroll
        for (int i = 0; i < 8; ++i) {
            a1[i] = f2bf((pv0[8 + i] - mu0) * rs0 * gc[ch0 + 8 + i] + betc[ch0 + 8 + i]);
            b1[i] = f2bf((pv1[8 + i] - mu1) * rs1 * gc[ch0 + 8 + i] + betc[ch0 + 8 + i]);
        }
        *(ushort8*)(dst)          = a0;
        *(ushort8*)(dst + 8)      = a1;
        *(ushort8*)(dst + CC)     = b0;
        *(ushort8*)(dst + CC + 8) = b1;
    } else {
        // ---------------- weight transpose (tail filler) ----------------
        const int u = bid - 768;
        const int x = u & 15, y = (u >> 4) & 7, z = u >> 7;
        const float* W; __hip_bfloat16* Wt; int K;
        switch (z) {
            case 0: W = Wq; Wt = Wqt; K = CQ; break;
            case 1: W = Wk; Wt = Wkt; K = CC; break;
            case 2: W = Wv; Wt = Wvt; K = CC; break;
            default: W = Wo; Wt = Wot; K = CQ; break;
        }
        const int k0 = x * 32;
        if (k0 >= K) return;
        const int c0 = y * 32;
        const int tx = tid & 31, ty = tid >> 5;
        #pragma unroll
        for (int i = 0; i < 4; ++i) {
            const int r = ty + 8 * i;
            T[r][tx] = W[(size_t)(k0 + r) * CQ + c0 + tx];
        }
        __syncthreads();
        #pragma unroll
        for (int i = 0; i < 4; ++i) {
            const int r = ty + 8 * i;
            Wt[(size_t)(c0 + r) * K + k0 + tx] = __float2bfloat16(T[tx][r]);
        }
    }
}

// ---------------------------------------------------------------------------
// proj_all_k: Q projection (z>=8) and fused K+V projection (z<8) in one
// launch, reg-staged global prefetch. V columns written PERMUTED per
// 16-block (groups-of-4 1<->2 swap) so attention reads contiguous PV B-frags.
// grid (16, 4, 16), block 256.  [R9-exact]
// ---------------------------------------------------------------------------
__global__ __launch_bounds__(256) void proj_all_k(
    const __hip_bfloat16* __restrict__ qn, const __hip_bfloat16* __restrict__ cn,
    const __hip_bfloat16* __restrict__ Wqt, const __hip_bfloat16* __restrict__ Wkt,
    const __hip_bfloat16* __restrict__ Wvt,
    const float* __restrict__ bq, const float* __restrict__ bk,
    const float* __restrict__ bv,
    __hip_bfloat16* __restrict__ Qb, __hip_bfloat16* __restrict__ Kb,
    __hip_bfloat16* __restrict__ Vt, float qsc) {
    __shared__ unsigned short As[64][40];
    __shared__ unsigned short B1[64][40];
    __shared__ unsigned short B2[64][40];

    const int zz = blockIdx.z;
    const int n0 = blockIdx.x * 64;
    const int c0 = blockIdx.y * 64;
    const int tid = threadIdx.x;
    const int wid = tid >> 6, lane = tid & 63;
    const int lg = lane >> 4, ln = lane & 15;
    const int wn0 = (wid & 1) * 32, wc0 = (wid >> 1) * 32;
    const int sr = tid >> 2;
    const int sk = (tid & 3) * 8;

    if (zz >= 8) {
        // ---------------- Q projection (K = 256) ----------------
        const int b = zz - 8;
        const unsigned short* Ab = (const unsigned short*)qn + ((size_t)b * N_ + n0) * CQ;
        const unsigned short* Wb = (const unsigned short*)Wqt + (size_t)c0 * CQ;
        f32x4 acc[2][2] = {};
        ushort8 ra = *(const ushort8*)(Ab + (size_t)sr * CQ + sk);
        ushort8 rw = *(const ushort8*)(Wb + (size_t)sr * CQ + sk);
        for (int t = 0; t < 8; ++t) {
            *(ushort8*)&As[sr][sk] = ra;
            *(ushort8*)&B1[sr][sk] = rw;
            __syncthreads();
            if (t < 7) {
                ra = *(const ushort8*)(Ab + (size_t)sr * CQ + (t + 1) * 32 + sk);
                rw = *(const ushort8*)(Wb + (size_t)sr * CQ + (t + 1) * 32 + sk);
            }
            bf16x8 a[2], w[2];
            #pragma unroll
            for (int i = 0; i < 2; ++i) a[i] = ldb8(&As[wn0 + 16 * i + ln][8 * lg]);
            #pragma unroll
            for (int j = 0; j < 2; ++j) w[j] = ldb8(&B1[wc0 + 16 * j + ln][8 * lg]);
            #pragma unroll
            for (int i = 0; i < 2; ++i)
                #pragma unroll
                for (int j = 0; j < 2; ++j)
                    acc[i][j] = __builtin_amdgcn_mfma_f32_16x16x32_bf16(a[i], w[j], acc[i][j], 0, 0, 0);
            __syncthreads();
        }
        #pragma unroll
        for (int j = 0; j < 2; ++j) {
            const int co = c0 + wc0 + 16 * j + ln;
            const int h = co >> 5, d = co & 31;
            const float bb = bq[co];
            #pragma unroll
            for (int i = 0; i < 2; ++i)
                #pragma unroll
                for (int r = 0; r < 4; ++r) {
                    const int n = n0 + wn0 + 16 * i + 4 * lg + r;
                    Qb[(((size_t)b * NH + h) * N_ + n) * HD + d] =
                        __float2bfloat16((acc[i][j][r] + bb) * qsc);
                }
        }
    } else {
        // ---------------- K + V projection (K = 512) ----------------
        const int b = zz;
        const unsigned short* Ab  = (const unsigned short*)cn + ((size_t)b * N_ + n0) * CC;
        const unsigned short* Wkb = (const unsigned short*)Wkt + (size_t)c0 * CC;
        const unsigned short* Wvb = (const unsigned short*)Wvt + (size_t)c0 * CC;
        f32x4 accK[2][2] = {};
        f32x4 accV[2][2] = {};
        ushort8 ra = *(const ushort8*)(Ab  + (size_t)sr * CC + sk);
        ushort8 rk = *(const ushort8*)(Wkb + (size_t)sr * CC + sk);
        ushort8 rv = *(const ushort8*)(Wvb + (size_t)sr * CC + sk);
        for (int t = 0; t < 16; ++t) {
            *(ushort8*)&As[sr][sk] = ra;
            *(ushort8*)&B1[sr][sk] = rk;
            *(ushort8*)&B2[sr][sk] = rv;
            __syncthreads();
            if (t < 15) {
                ra = *(const ushort8*)(Ab  + (size_t)sr * CC + (t + 1) * 32 + sk);
                rk = *(const ushort8*)(Wkb + (size_t)sr * CC + (t + 1) * 32 + sk);
                rv = *(const ushort8*)(Wvb + (size_t)sr * CC + (t + 1) * 32 + sk);
            }
            bf16x8 a[2], wk[2], wv[2];
            #pragma unroll
            for (int i = 0; i < 2; ++i) {
                a[i]  = ldb8(&As[wn0 + 16 * i + ln][8 * lg]);
                wk[i] = ldb8(&B1[wc0 + 16 * i + ln][8 * lg]);
                wv[i] = ldb8(&B2[wc0 + 16 * i + ln][8 * lg]);
            }
            #pragma unroll
            for (int i = 0; i < 2; ++i)
                #pragma unroll
                for (int j = 0; j < 2; ++j) {
                    accK[i][j] = __builtin_amdgcn_mfma_f32_16x16x32_bf16(a[i], wk[j], accK[i][j], 0, 0, 0);
                    accV[i][j] = __builtin_amdgcn_mfma_f32_16x16x32_bf16(a[i], wv[j], accV[i][j], 0, 0, 0);
                }
            __syncthreads();
        }
        #pragma unroll
        for (int j = 0; j < 2; ++j) {
            const int co = c0 + wc0 + 16 * j + ln;
            const int h = co >> 5, d = co & 31;
            const float bbk = bk[co], bbv = bv[co];
            #pragma unroll
            for (int i = 0; i < 2; ++i) {
                const int nb = n0 + wn0 + 16 * i + 4 * lg;
                #pragma unroll
                for (int r = 0; r < 4; ++r)
                    Kb[(((size_t)b * NH + h) * N_ + nb + r) * HD + d] =
                        __float2bfloat16(accK[i][j][r] + bbk);
                ushort4v o;
                #pragma unroll
                for (int r = 0; r < 4; ++r) o[r] = f2bf(accV[i][j][r] + bbv);
                const int g  = (nb >> 2) & 3;
                const int gp = ((g & 1) << 1) | (g >> 1);
                const int nbp = (nb & ~15) | (gp << 2);
                *(ushort4v*)((unsigned short*)Vt + (((size_t)b * NH + h) * HD + d) * N_ + nbp) = o;
            }
        }
    }
}

// ---------------------------------------------------------------------------
// 32x32 swapped-QK^T flash attention, in-register max-free softmax,
// 2-deep K prefetch + top-of-step V loads. grid (16, 64) XCD-swizzled.
// [R9-exact]
// ---------------------------------------------------------------------------
__global__ __launch_bounds__(256) void attn32_k(
    const __hip_bfloat16* __restrict__ Q,
    const __hip_bfloat16* __restrict__ K,
    const __hip_bfloat16* __restrict__ Vt,
    __hip_bfloat16* __restrict__ O) {
    __shared__ float accS[2][64][20];
    __shared__ float lwS[2][64];

    const int lin = blockIdx.x + 16 * blockIdx.y;
    const int eff = (lin & 7) * 128 + (lin >> 3);
    const int qt  = eff & 15;
    const int bh  = eff >> 4;
    const int b   = bh >> 3;
    const int h   = bh & 7;
    const int wid  = threadIdx.x >> 6;
    const int lane = threadIdx.x & 63;
    const int l31  = lane & 31;
    const int hh   = lane >> 5;
    const int qsub = wid >> 1;
    const int kvh  = wid & 1;
    const int q0   = qt * 64 + qsub * 32;

    const unsigned short* Qp = (const unsigned short*)Q + ((size_t)bh * N_ + q0) * HD;
    const unsigned short* Kbb = (const unsigned short*)K + (size_t)bh * N_ * HD;
    const unsigned short* Vb = (const unsigned short*)Vt + ((size_t)bh * HD + l31) * N_;

    bf16x8 qB[2];
    #pragma unroll
    for (int m = 0; m < 2; ++m)
        qB[m] = ldb8(Qp + (size_t)l31 * HD + 16 * m + 8 * hh);

    const f32x16 Z = {0.f,0.f,0.f,0.f,0.f,0.f,0.f,0.f,
                      0.f,0.f,0.f,0.f,0.f,0.f,0.f,0.f};
    f32x16 acc = Z;
    float ls0 = 0.f, ls1 = 0.f, ls2 = 0.f, ls3 = 0.f;

    const int kvbase = kvh * 512;
    const unsigned short* kp = Kbb + (size_t)(kvbase + l31) * HD + 8 * hh;
    const unsigned short* vp = Vb + kvbase + 8 * hh;

    bf16x8 kaA[2][4];
    #pragma unroll
    for (int j = 0; j < 4; ++j)
        kaA[0][j] = ldb8(kp + (j >> 1) * 1024 + (j & 1) * 16);

    #pragma unroll
    for (int st = 0; st < 8; ++st) {
        const int cur = st & 1;
        bf16x8 va[4];
        #pragma unroll
        for (int j = 0; j < 4; ++j)
            va[j] = ldb8(vp + st * 64 + 16 * j);
        if (st < 7) {
            const unsigned short* kp2 = kp + (size_t)(st + 1) * 2048;
            #pragma unroll
            for (int j = 0; j < 4; ++j)
                kaA[cur ^ 1][j] = ldb8(kp2 + (j >> 1) * 1024 + (j & 1) * 16);
        }

        f32x16 s0, s1;
        s0 = __builtin_amdgcn_mfma_f32_32x32x16_bf16(kaA[cur][0], qB[0], Z, 0, 0, 0);
        s0 = __builtin_amdgcn_mfma_f32_32x32x16_bf16(kaA[cur][1], qB[1], s0, 0, 0, 0);
        s1 = __builtin_amdgcn_mfma_f32_32x32x16_bf16(kaA[cur][2], qB[0], Z, 0, 0, 0);
        s1 = __builtin_amdgcn_mfma_f32_32x32x16_bf16(kaA[cur][3], qB[1], s1, 0, 0, 0);

        unsigned int pk[2][4][2];
        #pragma unroll
        for (int T = 0; T < 2; ++T) {
            float p[16];
            #pragma unroll
            for (int r = 0; r < 16; ++r)
                p[r] = __builtin_amdgcn_exp2f(T == 0 ? s0[r] : s1[r]);
            #pragma unroll
            for (int r = 0; r < 16; r += 4) {
                ls0 += p[r]; ls1 += p[r + 1]; ls2 += p[r + 2]; ls3 += p[r + 3];
            }
            #pragma unroll
            for (int c = 0; c < 4; ++c) {
                asm("v_cvt_pk_bf16_f32 %0, %1, %2"
                    : "=v"(pk[T][c][0]) : "v"(p[4 * c]), "v"(p[4 * c + 1]));
                asm("v_cvt_pk_bf16_f32 %0, %1, %2"
                    : "=v"(pk[T][c][1]) : "v"(p[4 * c + 2]), "v"(p[4 * c + 3]));
            }
        }

        #pragma unroll
        for (int w = 0; w < 4; ++w) {
            const int T = w >> 1, cp = w & 1;
            uint4v fu = {pk[T][2 * cp][0], pk[T][2 * cp][1],
                         pk[T][2 * cp + 1][0], pk[T][2 * cp + 1][1]};
            const bf16x8 pa = __builtin_bit_cast(bf16x8, fu);
            acc = __builtin_amdgcn_mfma_f32_32x32x16_bf16(pa, va[w], acc, 0, 0, 0);
        }
    }

    const float lsum = (ls0 + ls1) + (ls2 + ls3);
    const float lw = lsum + __shfl_xor(lsum, 32);

    if (kvh == 1) {
        #pragma unroll
        for (int r4 = 0; r4 < 4; ++r4) {
            float4 v = {acc[4 * r4], acc[4 * r4 + 1], acc[4 * r4 + 2], acc[4 * r4 + 3]};
            *(float4*)&accS[qsub][lane][4 * r4] = v;
        }
        lwS[qsub][lane] = lw;
    }
    __syncthreads();
    if (kvh == 0) {
        const float linv = 1.0f / (lw + lwS[qsub][lane]);
        #pragma unroll
        for (int r = 0; r < 16; ++r) {
            const int ql = (r & 3) + 8 * (r >> 2) + 4 * hh;
            const float vv = (acc[r] + accS[qsub][lane][r]) * __shfl(linv, ql);
            O[((size_t)b * N_ + q0 + ql) * CQ + h * HD + l31] = __float2bfloat16(vv);
        }
    }
}

// ---------------------------------------------------------------------------
// Output projection + bias + bf16 residual, reg-staged prefetch.
// grid (16, 4, B), block 256.  [R15-exact]
// ---------------------------------------------------------------------------
__global__ __launch_bounds__(256) void out_proj_k(const __hip_bfloat16* __restrict__ Ob,
                              const __hip_bfloat16* __restrict__ Wot,
                              const float* __restrict__ bo,
                              const __hip_bfloat16* __restrict__ qraw,
                              float* __restrict__ out) {
    __shared__ unsigned short As[64][40];
    __shared__ unsigned short Bs[64][40];
    const int b  = blockIdx.z;
    const int n0 = blockIdx.x * 64;
    const int c0 = blockIdx.y * 64;
    const int tid = threadIdx.x;
    const int wid = tid >> 6, lane = tid & 63;
    const int lg = lane >> 4, ln = lane & 15;
    const int wn0 = (wid & 1) * 32, wc0 = (wid >> 1) * 32;

    const unsigned short* Ab = (const unsigned short*)Ob + ((size_t)b * N_ + n0) * CQ;
    const unsigned short* Wb = (const unsigned short*)Wot + (size_t)c0 * CQ;
    const int sr = tid >> 2;
    const int sk = (tid & 3) * 8;

    f32x4 acc[2][2] = {};
    ushort8 ra = *(const ushort8*)(Ab + (size_t)sr * CQ + sk);
    ushort8 rw = *(const ushort8*)(Wb + (size_t)sr * CQ + sk);

    for (int t = 0; t < 8; ++t) {
        *(ushort8*)&As[sr][sk] = ra;
        *(ushort8*)&Bs[sr][sk] = rw;
        __syncthreads();
        if (t < 7) {
            ra = *(const ushort8*)(Ab + (size_t)sr * CQ + (t + 1) * 32 + sk);
            rw = *(const ushort8*)(Wb + (size_t)sr * CQ + (t + 1) * 32 + sk);
        }
        bf16x8 a[2], w[2];
        #pragma unroll
        for (int i = 0; i < 2; ++i)
            a[i] = ldb8(&As[wn0 + 16 * i + ln][8 * lg]);
        #pragma unroll
        for (int j = 0; j < 2; ++j)
            w[j] = ldb8(&Bs[wc0 + 16 * j + ln][8 * lg]);
        #pragma unroll
        for (int i = 0; i < 2; ++i)
            #pragma unroll
            for (int j = 0; j < 2; ++j)
                acc[i][j] = __builtin_amdgcn_mfma_f32_16x16x32_bf16(a[i], w[j], acc[i][j], 0, 0, 0);
        __syncthreads();
    }

    #pragma unroll
    for (int j = 0; j < 2; ++j) {
        const int co = c0 + wc0 + 16 * j + ln;
        const float bb = bo[co];
        #pragma unroll
        for (int i = 0; i < 2; ++i) {
            const int nb = n0 + wn0 + 16 * i + 4 * lg;
            const ushort4v res = *(const ushort4v*)((const unsigned short*)qraw
                + ((size_t)b * CQ + co) * N_ + nb);
            float4 o;
            o.x = acc[i][j][0] + bb + bf2f(res[0]);
            o.y = acc[i][j][1] + bb + bf2f(res[1]);
            o.z = acc[i][j][2] + bb + bf2f(res[2]);
            o.w = acc[i][j][3] + bb + bf2f(res[3]);
            *(float4*)&out[((size_t)b * CQ + co) * N_ + nb] = o;
        }
    }
}

// ---------------------------------------------------------------------------
extern "C" void kernel_launch(void* const* d_in, const int* in_sizes, int n_in,
                              void* d_out, int out_size, void* d_ws, size_t ws_size,
                              hipStream_t stream) {
    const float* query   = (const float*)d_in[0];
    const float* context = (const float*)d_in[1];
    const float* Wq = (const float*)d_in[2];
    const float* bq = (const float*)d_in[3];
    const float* Wk = (const float*)d_in[4];
    const float* bk = (const float*)d_in[5];
    const float* Wv = (const float*)d_in[6];
    const float* bv = (const float*)d_in[7];
    const float* Wo = (const float*)d_in[8];
    const float* bo = (const float*)d_in[9];
    const float* gq   = (const float*)d_in[10];
    const float* betq = (const float*)d_in[11];
    const float* gc   = (const float*)d_in[12];
    const float* betc = (const float*)d_in[13];
    float* out = (float*)d_out;

    char* w = (char*)d_ws;
    __hip_bfloat16* qn   = (__hip_bfloat16*)w;  w += (size_t)B_ * N_ * CQ * 2;
    __hip_bfloat16* cn   = (__hip_bfloat16*)w;  w += (size_t)B_ * N_ * CC * 2;
    __hip_bfloat16* qraw = (__hip_bfloat16*)w;  w += (size_t)B_ * CQ * N_ * 2;
    __hip_bfloat16* Qb   = (__hip_bfloat16*)w;  w += (size_t)B_ * NH * N_ * HD * 2;
    __hip_bfloat16* Kb   = (__hip_bfloat16*)w;  w += (size_t)B_ * NH * N_ * HD * 2;
    __hip_bfloat16* Vt   = (__hip_bfloat16*)w;  w += (size_t)B_ * NH * HD * N_ * 2;
    __hip_bfloat16* Ob   = (__hip_bfloat16*)w;  w += (size_t)B_ * N_ * CQ * 2;
    __hip_bfloat16* Wqt  = (__hip_bfloat16*)w;  w += (size_t)CQ * CQ * 2;
    __hip_bfloat16* Wkt  = (__hip_bfloat16*)w;  w += (size_t)CQ * CC * 2;
    __hip_bfloat16* Wvt  = (__hip_bfloat16*)w;  w += (size_t)CQ * CC * 2;
    __hip_bfloat16* Wot  = (__hip_bfloat16*)w;  w += (size_t)CQ * CQ * 2;

    prep_k<<<dim3(1280), 256, 0, stream>>>(query, context, Wq, Wk, Wv, Wo,
                                           gq, betq, gc, betc,
                                           Wqt, Wkt, Wvt, Wot, qn, cn, qraw);

    // scale includes log2(e) so the softmax exp becomes a bare v_exp_f32
    const float qsc = 0.17677669529663687f * 1.4426950408889634f;
    proj_all_k<<<dim3(16, 4, 16), 256, 0, stream>>>(qn, cn, Wqt, Wkt, Wvt,
                                                    bq, bk, bv, Qb, Kb, Vt, qsc);

    attn32_k<<<dim3(16, 64), 256, 0, stream>>>(Qb, Kb, Vt, Ob);

    out_proj_k<<<dim3(16, 4, 8), 256, 0, stream>>>(Ob, Wot, bo, qraw, out);
}

// Round 17
// 64.831 us; speedup vs baseline: 1.0844x; 1.0276x over previous
//
#include <hip/hip_runtime.h>
#include <hip/hip_bf16.h>
#include <cstddef>

#define B_  8
#define CQ  256
#define CC  512
#define N_  1024   // Hq*Wq
#define HQ  32
#define WQ  32
#define NH  8
#define HD  32

typedef __bf16 bf16x8 __attribute__((ext_vector_type(8)));
typedef float f32x4 __attribute__((ext_vector_type(4)));
typedef float f32x16 __attribute__((ext_vector_type(16)));
typedef unsigned int uint4v __attribute__((ext_vector_type(4)));
typedef unsigned short ushort8 __attribute__((ext_vector_type(8)));
typedef unsigned short ushort4v __attribute__((ext_vector_type(4)));

__device__ __forceinline__ unsigned short f2bf(float x) {
    return __builtin_bit_cast(unsigned short, __float2bfloat16(x));
}
__device__ __forceinline__ float bf2f(unsigned short x) {
    return __bfloat162float(__builtin_bit_cast(__hip_bfloat16, x));
}
__device__ __forceinline__ bf16x8 ldb8(const unsigned short* p) {
    return __builtin_bit_cast(bf16x8, *(const ushort8*)p);
}

// ---------------------------------------------------------------------------
// prep_k (1280 blocks x 256), long-pole-first dispatch.  [R16-exact]
//   [0,256):    LN(query) -> qn bf16 + qraw bf16 (256 blocks, 32 pos each)
//   [256,768):  pool+LN(context) -> cn bf16
//   [768,1280): weight transpose f32->bf16
// ---------------------------------------------------------------------------
__global__ __launch_bounds__(256) void prep_k(
    const float* __restrict__ query, const float* __restrict__ context,
    const float* __restrict__ Wq, const float* __restrict__ Wk,
    const float* __restrict__ Wv, const float* __restrict__ Wo,
    const float* __restrict__ gq, const float* __restrict__ betq,
    const float* __restrict__ gc, const float* __restrict__ betc,
    __hip_bfloat16* __restrict__ Wqt, __hip_bfloat16* __restrict__ Wkt,
    __hip_bfloat16* __restrict__ Wvt, __hip_bfloat16* __restrict__ Wot,
    __hip_bfloat16* __restrict__ qn, __hip_bfloat16* __restrict__ cn,
    __hip_bfloat16* __restrict__ qraw) {
    __shared__ float T[32][33];
    __shared__ float SsA[32][16];
    __shared__ float S2A[32][16];
    __shared__ float SsB[32][32];
    __shared__ float S2B[32][32];
    __shared__ float Mu[32], Rs[32];

    const int bid = blockIdx.x;
    const int tid = threadIdx.x;

    if (bid < 256) {
        // --------- LN(query) + qraw: 256 blocks, 32 positions each ---------
        const int nt = bid & 31, b = bid >> 5;
        const int nq = tid & 7;
        const int cg = tid >> 3;
        const int ch0 = cg * 8;
        const int nb  = nt * 32 + 4 * nq;

        const float* Qb = query + ((size_t)b * CQ + ch0) * N_ + nb;
        float qv[32];
        float ps[4] = {0.f, 0.f, 0.f, 0.f};
        float p2[4] = {0.f, 0.f, 0.f, 0.f};
        #pragma unroll
        for (int i = 0; i < 8; ++i) {
            const float4 v = *(const float4*)(Qb + (size_t)i * N_);
            qv[4 * i + 0] = v.x; qv[4 * i + 1] = v.y;
            qv[4 * i + 2] = v.z; qv[4 * i + 3] = v.w;
            ps[0] += v.x; p2[0] += v.x * v.x;
            ps[1] += v.y; p2[1] += v.y * v.y;
            ps[2] += v.z; p2[2] += v.z * v.z;
            ps[3] += v.w; p2[3] += v.w * v.w;
        }
        #pragma unroll
        for (int i = 0; i < 8; ++i) {
            ushort4v o;
            o[0] = f2bf(qv[4 * i + 0]); o[1] = f2bf(qv[4 * i + 1]);
            o[2] = f2bf(qv[4 * i + 2]); o[3] = f2bf(qv[4 * i + 3]);
            *(ushort4v*)((unsigned short*)qraw + ((size_t)b * CQ + ch0 + i) * N_ + nb) = o;
        }
        #pragma unroll
        for (int j = 0; j < 4; ++j) {
            SsB[cg][4 * nq + j] = ps[j];
            S2B[cg][4 * nq + j] = p2[j];
        }
        __syncthreads();
        if (tid < 32) {
            float ts = 0.f, t2 = 0.f;
            #pragma unroll
            for (int i = 0; i < 32; ++i) { ts += SsB[i][tid]; t2 += S2B[i][tid]; }
            const float mu  = ts * (1.f / CQ);
            const float var = t2 * (1.f / CQ) - mu * mu;
            Mu[tid] = mu; Rs[tid] = rsqrtf(var + 1e-5f);
        }
        __syncthreads();
        #pragma unroll
        for (int j = 0; j < 4; ++j) {
            const float mu = Mu[4 * nq + j], rs = Rs[4 * nq + j];
            ushort8 o;
            #pragma unroll
            for (int i = 0; i < 8; ++i)
                o[i] = f2bf((qv[4 * i + j] - mu) * rs * gq[ch0 + i] + betq[ch0 + i]);
            *(ushort8*)((unsigned short*)qn + ((size_t)b * N_ + nb + j) * CQ + ch0) = o;
        }
    } else if (bid < 768) {
        // ------- pool + LN(context): float4 loads, register-resident -------
        const int u    = bid - 256;
        const int wqc2 = u & 1, hq = (u >> 1) & 31, b = u >> 6;
        const int pp   = tid & 7;
        const int cg   = tid >> 3;
        const int ch0  = cg * 16;

        const float* Cb = context + ((size_t)b * CC + ch0) * 4096
                        + (size_t)(2 * hq) * 64 + (32 * wqc2 + 4 * pp);
        float pv0[16], pv1[16];
        float ss0 = 0.f, ss1 = 0.f, s20 = 0.f, s21 = 0.f;
        #pragma unroll
        for (int i = 0; i < 16; ++i) {
            const float4 r0 = *(const float4*)(Cb + (size_t)i * 4096);
            const float4 r1 = *(const float4*)(Cb + (size_t)i * 4096 + 64);
            const float v0 = (r0.x + r0.y + r1.x + r1.y) * 0.25f;
            const float v1 = (r0.z + r0.w + r1.z + r1.w) * 0.25f;
            pv0[i] = v0; pv1[i] = v1;
            ss0 += v0; s20 += v0 * v0;
            ss1 += v1; s21 += v1 * v1;
        }
        SsA[cg][2 * pp]     = ss0; S2A[cg][2 * pp]     = s20;
        SsA[cg][2 * pp + 1] = ss1; S2A[cg][2 * pp + 1] = s21;
        __syncthreads();
        if (tid < 16) {
            float ts = 0.f, t2 = 0.f;
            #pragma unroll
            for (int i = 0; i < 32; ++i) { ts += SsA[i][tid]; t2 += S2A[i][tid]; }
            const float mu  = ts * (1.f / CC);
            const float var = t2 * (1.f / CC) - mu * mu;
            Mu[tid] = mu; Rs[tid] = rsqrtf(var + 1e-5f);
        }
        __syncthreads();
        const float mu0 = Mu[2 * pp],     rs0 = Rs[2 * pp];
        const float mu1 = Mu[2 * pp + 1], rs1 = Rs[2 * pp + 1];
        const int pos0 = hq * 32 + wqc2 * 16 + 2 * pp;
        unsigned short* dst = (unsigned short*)cn
            + ((size_t)b * N_ + pos0) * CC + ch0;
        ushort8 a0, a1, b0, b1;
        #pragma unroll
        for (int i = 0; i < 8; ++i) {
            a0[i] = f2bf((pv0[i] - mu0) * rs0 * gc[ch0 + i] + betc[ch0 + i]);
            b0[i] = f2bf((pv1[i] - mu1) * rs1 * gc[ch0 + i] + betc[ch0 + i]);
        }
        #pragma unroll
        for (int i = 0; i < 8; ++i) {
            a1[i] = f2bf((pv0[8 + i] - mu0) * rs0 * gc[ch0 + 8 + i] + betc[ch0 + 8 + i]);
            b1[i] = f2bf((pv1[8 + i] - mu1) * rs1 * gc[ch0 + 8 + i] + betc[ch0 + 8 + i]);
        }
        *(ushort8*)(dst)          = a0;
        *(ushort8*)(dst + 8)      = a1;
        *(ushort8*)(dst + CC)     = b0;
        *(ushort8*)(dst + CC + 8) = b1;
    } else {
        // ---------------- weight transpose (tail filler) ----------------
        const int u = bid - 768;
        const int x = u & 15, y = (u >> 4) & 7, z = u >> 7;
        const float* W; __hip_bfloat16* Wt; int K;
        switch (z) {
            case 0: W = Wq; Wt = Wqt; K = CQ; break;
            case 1: W = Wk; Wt = Wkt; K = CC; break;
            case 2: W = Wv; Wt = Wvt; K = CC; break;
            default: W = Wo; Wt = Wot; K = CQ; break;
        }
        const int k0 = x * 32;
        if (k0 >= K) return;
        const int c0 = y * 32;
        const int tx = tid & 31, ty = tid >> 5;
        #pragma unroll
        for (int i = 0; i < 4; ++i) {
            const int r = ty + 8 * i;
            T[r][tx] = W[(size_t)(k0 + r) * CQ + c0 + tx];
        }
        __syncthreads();
        #pragma unroll
        for (int i = 0; i < 4; ++i) {
            const int r = ty + 8 * i;
            Wt[(size_t)(c0 + r) * K + k0 + tx] = __float2bfloat16(T[tx][r]);
        }
    }
}

// ---------------------------------------------------------------------------
// proj_all_k: Q projection (z>=8) and fused K+V projection (z<8), reg-staged
// prefetch, V columns PERMUTED per 16-block. grid (16,4,16).  [R9-exact]
// ---------------------------------------------------------------------------
__global__ __launch_bounds__(256) void proj_all_k(
    const __hip_bfloat16* __restrict__ qn, const __hip_bfloat16* __restrict__ cn,
    const __hip_bfloat16* __restrict__ Wqt, const __hip_bfloat16* __restrict__ Wkt,
    const __hip_bfloat16* __restrict__ Wvt,
    const float* __restrict__ bq, const float* __restrict__ bk,
    const float* __restrict__ bv,
    __hip_bfloat16* __restrict__ Qb, __hip_bfloat16* __restrict__ Kb,
    __hip_bfloat16* __restrict__ Vt, float qsc) {
    __shared__ unsigned short As[64][40];
    __shared__ unsigned short B1[64][40];
    __shared__ unsigned short B2[64][40];

    const int zz = blockIdx.z;
    const int n0 = blockIdx.x * 64;
    const int c0 = blockIdx.y * 64;
    const int tid = threadIdx.x;
    const int wid = tid >> 6, lane = tid & 63;
    const int lg = lane >> 4, ln = lane & 15;
    const int wn0 = (wid & 1) * 32, wc0 = (wid >> 1) * 32;
    const int sr = tid >> 2;
    const int sk = (tid & 3) * 8;

    if (zz >= 8) {
        const int b = zz - 8;
        const unsigned short* Ab = (const unsigned short*)qn + ((size_t)b * N_ + n0) * CQ;
        const unsigned short* Wb = (const unsigned short*)Wqt + (size_t)c0 * CQ;
        f32x4 acc[2][2] = {};
        ushort8 ra = *(const ushort8*)(Ab + (size_t)sr * CQ + sk);
        ushort8 rw = *(const ushort8*)(Wb + (size_t)sr * CQ + sk);
        for (int t = 0; t < 8; ++t) {
            *(ushort8*)&As[sr][sk] = ra;
            *(ushort8*)&B1[sr][sk] = rw;
            __syncthreads();
            if (t < 7) {
                ra = *(const ushort8*)(Ab + (size_t)sr * CQ + (t + 1) * 32 + sk);
                rw = *(const ushort8*)(Wb + (size_t)sr * CQ + (t + 1) * 32 + sk);
            }
            bf16x8 a[2], w[2];
            #pragma unroll
            for (int i = 0; i < 2; ++i) a[i] = ldb8(&As[wn0 + 16 * i + ln][8 * lg]);
            #pragma unroll
            for (int j = 0; j < 2; ++j) w[j] = ldb8(&B1[wc0 + 16 * j + ln][8 * lg]);
            #pragma unroll
            for (int i = 0; i < 2; ++i)
                #pragma unroll
                for (int j = 0; j < 2; ++j)
                    acc[i][j] = __builtin_amdgcn_mfma_f32_16x16x32_bf16(a[i], w[j], acc[i][j], 0, 0, 0);
            __syncthreads();
        }
        #pragma unroll
        for (int j = 0; j < 2; ++j) {
            const int co = c0 + wc0 + 16 * j + ln;
            const int h = co >> 5, d = co & 31;
            const float bb = bq[co];
            #pragma unroll
            for (int i = 0; i < 2; ++i)
                #pragma unroll
                for (int r = 0; r < 4; ++r) {
                    const int n = n0 + wn0 + 16 * i + 4 * lg + r;
                    Qb[(((size_t)b * NH + h) * N_ + n) * HD + d] =
                        __float2bfloat16((acc[i][j][r] + bb) * qsc);
                }
        }
    } else {
        const int b = zz;
        const unsigned short* Ab  = (const unsigned short*)cn + ((size_t)b * N_ + n0) * CC;
        const unsigned short* Wkb = (const unsigned short*)Wkt + (size_t)c0 * CC;
        const unsigned short* Wvb = (const unsigned short*)Wvt + (size_t)c0 * CC;
        f32x4 accK[2][2] = {};
        f32x4 accV[2][2] = {};
        ushort8 ra = *(const ushort8*)(Ab  + (size_t)sr * CC + sk);
        ushort8 rk = *(const ushort8*)(Wkb + (size_t)sr * CC + sk);
        ushort8 rv = *(const ushort8*)(Wvb + (size_t)sr * CC + sk);
        for (int t = 0; t < 16; ++t) {
            *(ushort8*)&As[sr][sk] = ra;
            *(ushort8*)&B1[sr][sk] = rk;
            *(ushort8*)&B2[sr][sk] = rv;
            __syncthreads();
            if (t < 15) {
                ra = *(const ushort8*)(Ab  + (size_t)sr * CC + (t + 1) * 32 + sk);
                rk = *(const ushort8*)(Wkb + (size_t)sr * CC + (t + 1) * 32 + sk);
                rv = *(const ushort8*)(Wvb + (size_t)sr * CC + (t + 1) * 32 + sk);
            }
            bf16x8 a[2], wk[2], wv[2];
            #pragma unroll
            for (int i = 0; i < 2; ++i) {
                a[i]  = ldb8(&As[wn0 + 16 * i + ln][8 * lg]);
                wk[i] = ldb8(&B1[wc0 + 16 * i + ln][8 * lg]);
                wv[i] = ldb8(&B2[wc0 + 16 * i + ln][8 * lg]);
            }
            #pragma unroll
            for (int i = 0; i < 2; ++i)
                #pragma unroll
                for (int j = 0; j < 2; ++j) {
                    accK[i][j] = __builtin_amdgcn_mfma_f32_16x16x32_bf16(a[i], wk[j], accK[i][j], 0, 0, 0);
                    accV[i][j] = __builtin_amdgcn_mfma_f32_16x16x32_bf16(a[i], wv[j], accV[i][j], 0, 0, 0);
                }
            __syncthreads();
        }
        #pragma unroll
        for (int j = 0; j < 2; ++j) {
            const int co = c0 + wc0 + 16 * j + ln;
            const int h = co >> 5, d = co & 31;
            const float bbk = bk[co], bbv = bv[co];
            #pragma unroll
            for (int i = 0; i < 2; ++i) {
                const int nb = n0 + wn0 + 16 * i + 4 * lg;
                #pragma unroll
                for (int r = 0; r < 4; ++r)
                    Kb[(((size_t)b * NH + h) * N_ + nb + r) * HD + d] =
                        __float2bfloat16(accK[i][j][r] + bbk);
                ushort4v o;
                #pragma unroll
                for (int r = 0; r < 4; ++r) o[r] = f2bf(accV[i][j][r] + bbv);
                const int g  = (nb >> 2) & 3;
                const int gp = ((g & 1) << 1) | (g >> 1);
                const int nbp = (nb & ~15) | (gp << 2);
                *(ushort4v*)((unsigned short*)Vt + (((size_t)b * NH + h) * HD + d) * N_ + nbp) = o;
            }
        }
    }
}

// ---------------------------------------------------------------------------
// attn_out_k: FUSED attention + output projection + bias + residual.
// 256 blocks x 1024 threads (1 block/CU). Block = 32 q-rows x ALL 8 heads x
// both kv-halves: wave wid = (kvh<<3)|h. Attention inner loop is R9-wave-
// identical. O tile lands in LDS (32x264 bf16); after one barrier the same
// 16 waves do the O-projection (A from LDS, Wot rows direct from L2),
// writing out f32 (B,CQ,N) with bias + bf16 residual.
// ---------------------------------------------------------------------------
__global__ __launch_bounds__(1024) void attn_out_k(
    const __hip_bfloat16* __restrict__ Q,
    const __hip_bfloat16* __restrict__ K,
    const __hip_bfloat16* __restrict__ Vt,
    const __hip_bfloat16* __restrict__ Wot,
    const float* __restrict__ bo,
    const __hip_bfloat16* __restrict__ qraw,
    float* __restrict__ out) {
    __shared__ float accS[8][64][20];         // 40 KB: kvh=1 partials per head
    __shared__ float lwS[8][64];              //  2 KB
    __shared__ unsigned short ObL[32][264];   // 16.5 KB: O tile [n][co]

    // XCD swizzle: 32 consecutive q-tiles of a b per XCD (256 blocks, 8 XCDs)
    const int lin = blockIdx.x;
    const int eff = (lin & 7) * 32 + (lin >> 3);
    const int qt  = eff & 31;
    const int b   = eff >> 5;
    const int wid  = threadIdx.x >> 6;    // 0..15
    const int lane = threadIdx.x & 63;
    const int l31  = lane & 31;
    const int hh   = lane >> 5;
    const int h    = wid & 7;
    const int kvh  = wid >> 3;
    const int q0   = qt * 32;
    const int bh   = b * NH + h;

    const unsigned short* Qp  = (const unsigned short*)Q + ((size_t)bh * N_ + q0) * HD;
    const unsigned short* Kbb = (const unsigned short*)K + (size_t)bh * N_ * HD;
    const unsigned short* Vb  = (const unsigned short*)Vt + ((size_t)bh * HD + l31) * N_;

    bf16x8 qB[2];
    #pragma unroll
    for (int m = 0; m < 2; ++m)
        qB[m] = ldb8(Qp + (size_t)l31 * HD + 16 * m + 8 * hh);

    const f32x16 Z = {0.f,0.f,0.f,0.f,0.f,0.f,0.f,0.f,
                      0.f,0.f,0.f,0.f,0.f,0.f,0.f,0.f};
    f32x16 acc = Z;
    float ls0 = 0.f, ls1 = 0.f, ls2 = 0.f, ls3 = 0.f;

    const int kvbase = kvh * 512;
    const unsigned short* kp = Kbb + (size_t)(kvbase + l31) * HD + 8 * hh;
    const unsigned short* vp = Vb + kvbase + 8 * hh;

    bf16x8 kaA[2][4];
    #pragma unroll
    for (int j = 0; j < 4; ++j)
        kaA[0][j] = ldb8(kp + (j >> 1) * 1024 + (j & 1) * 16);

    #pragma unroll
    for (int st = 0; st < 8; ++st) {
        const int cur = st & 1;
        bf16x8 va[4];
        #pragma unroll
        for (int j = 0; j < 4; ++j)
            va[j] = ldb8(vp + st * 64 + 16 * j);
        if (st < 7) {
            const unsigned short* kp2 = kp + (size_t)(st + 1) * 2048;
            #pragma unroll
            for (int j = 0; j < 4; ++j)
                kaA[cur ^ 1][j] = ldb8(kp2 + (j >> 1) * 1024 + (j & 1) * 16);
        }

        f32x16 s0, s1;
        s0 = __builtin_amdgcn_mfma_f32_32x32x16_bf16(kaA[cur][0], qB[0], Z, 0, 0, 0);
        s0 = __builtin_amdgcn_mfma_f32_32x32x16_bf16(kaA[cur][1], qB[1], s0, 0, 0, 0);
        s1 = __builtin_amdgcn_mfma_f32_32x32x16_bf16(kaA[cur][2], qB[0], Z, 0, 0, 0);
        s1 = __builtin_amdgcn_mfma_f32_32x32x16_bf16(kaA[cur][3], qB[1], s1, 0, 0, 0);

        unsigned int pk[2][4][2];
        #pragma unroll
        for (int T = 0; T < 2; ++T) {
            float p[16];
            #pragma unroll
            for (int r = 0; r < 16; ++r)
                p[r] = __builtin_amdgcn_exp2f(T == 0 ? s0[r] : s1[r]);
            #pragma unroll
            for (int r = 0; r < 16; r += 4) {
                ls0 += p[r]; ls1 += p[r + 1]; ls2 += p[r + 2]; ls3 += p[r + 3];
            }
            #pragma unroll
            for (int c = 0; c < 4; ++c) {
                asm("v_cvt_pk_bf16_f32 %0, %1, %2"
                    : "=v"(pk[T][c][0]) : "v"(p[4 * c]), "v"(p[4 * c + 1]));
                asm("v_cvt_pk_bf16_f32 %0, %1, %2"
                    : "=v"(pk[T][c][1]) : "v"(p[4 * c + 2]), "v"(p[4 * c + 3]));
            }
        }

        #pragma unroll
        for (int w = 0; w < 4; ++w) {
            const int T = w >> 1, cp = w & 1;
            uint4v fu = {pk[T][2 * cp][0], pk[T][2 * cp][1],
                         pk[T][2 * cp + 1][0], pk[T][2 * cp + 1][1]};
            const bf16x8 pa = __builtin_bit_cast(bf16x8, fu);
            acc = __builtin_amdgcn_mfma_f32_32x32x16_bf16(pa, va[w], acc, 0, 0, 0);
        }
    }

    const float lsum = (ls0 + ls1) + (ls2 + ls3);
    const float lw = lsum + __shfl_xor(lsum, 32);

    if (kvh == 1) {
        #pragma unroll
        for (int r4 = 0; r4 < 4; ++r4) {
            float4 v = {acc[4 * r4], acc[4 * r4 + 1], acc[4 * r4 + 2], acc[4 * r4 + 3]};
            *(float4*)&accS[h][lane][4 * r4] = v;
        }
        lwS[h][lane] = lw;
    }
    __syncthreads();
    if (kvh == 0) {
        const float linv = 1.0f / (lw + lwS[h][lane]);
        #pragma unroll
        for (int r = 0; r < 16; ++r) {
            const int ql = (r & 3) + 8 * (r >> 2) + 4 * hh;
            const float vv = (acc[r] + accS[h][lane][r]) * __shfl(linv, ql);
            ObL[ql][h * HD + l31] = f2bf(vv);
        }
    }
    __syncthreads();

    // ---- O-projection: 32n x 256co; wave wid handles co [16*wid, 16*wid+16)
    const int lg = lane >> 4, ln = lane & 15;
    const int co0 = wid * 16;
    const unsigned short* Wb = (const unsigned short*)Wot + (size_t)co0 * CQ;

    f32x4 acc2[2] = {};
    #pragma unroll
    for (int t = 0; t < 8; ++t) {
        const int k0 = t * 32;
        const bf16x8 w = ldb8(Wb + (size_t)ln * CQ + k0 + 8 * lg);
        #pragma unroll
        for (int i = 0; i < 2; ++i) {
            const bf16x8 a = ldb8(&ObL[16 * i + ln][k0 + 8 * lg]);
            acc2[i] = __builtin_amdgcn_mfma_f32_16x16x32_bf16(a, w, acc2[i], 0, 0, 0);
        }
    }

    const int co = co0 + ln;
    const float bb = bo[co];
    #pragma unroll
    for (int i = 0; i < 2; ++i) {
        const int nb = q0 + 16 * i + 4 * lg;
        const ushort4v res = *(const ushort4v*)((const unsigned short*)qraw
            + ((size_t)b * CQ + co) * N_ + nb);
        float4 o;
        o.x = acc2[i][0] + bb + bf2f(res[0]);
        o.y = acc2[i][1] + bb + bf2f(res[1]);
        o.z = acc2[i][2] + bb + bf2f(res[2]);
        o.w = acc2[i][3] + bb + bf2f(res[3]);
        *(float4*)&out[((size_t)b * CQ + co) * N_ + nb] = o;
    }
}

// ---------------------------------------------------------------------------
extern "C" void kernel_launch(void* const* d_in, const int* in_sizes, int n_in,
                              void* d_out, int out_size, void* d_ws, size_t ws_size,
                              hipStream_t stream) {
    const float* query   = (const float*)d_in[0];
    const float* context = (const float*)d_in[1];
    const float* Wq = (const float*)d_in[2];
    const float* bq = (const float*)d_in[3];
    const float* Wk = (const float*)d_in[4];
    const float* bk = (const float*)d_in[5];
    const float* Wv = (const float*)d_in[6];
    const float* bv = (const float*)d_in[7];
    const float* Wo = (const float*)d_in[8];
    const float* bo = (const float*)d_in[9];
    const float* gq   = (const float*)d_in[10];
    const float* betq = (const float*)d_in[11];
    const float* gc   = (const float*)d_in[12];
    const float* betc = (const float*)d_in[13];
    float* out = (float*)d_out;

    char* w = (char*)d_ws;
    __hip_bfloat16* qn   = (__hip_bfloat16*)w;  w += (size_t)B_ * N_ * CQ * 2;
    __hip_bfloat16* cn   = (__hip_bfloat16*)w;  w += (size_t)B_ * N_ * CC * 2;
    __hip_bfloat16* qraw = (__hip_bfloat16*)w;  w += (size_t)B_ * CQ * N_ * 2;
    __hip_bfloat16* Qb   = (__hip_bfloat16*)w;  w += (size_t)B_ * NH * N_ * HD * 2;
    __hip_bfloat16* Kb   = (__hip_bfloat16*)w;  w += (size_t)B_ * NH * N_ * HD * 2;
    __hip_bfloat16* Vt   = (__hip_bfloat16*)w;  w += (size_t)B_ * NH * HD * N_ * 2;
    __hip_bfloat16* Wqt  = (__hip_bfloat16*)w;  w += (size_t)CQ * CQ * 2;
    __hip_bfloat16* Wkt  = (__hip_bfloat16*)w;  w += (size_t)CQ * CC * 2;
    __hip_bfloat16* Wvt  = (__hip_bfloat16*)w;  w += (size_t)CQ * CC * 2;
    __hip_bfloat16* Wot  = (__hip_bfloat16*)w;  w += (size_t)CQ * CQ * 2;

    prep_k<<<dim3(1280), 256, 0, stream>>>(query, context, Wq, Wk, Wv, Wo,
                                           gq, betq, gc, betc,
                                           Wqt, Wkt, Wvt, Wot, qn, cn, qraw);

    // scale includes log2(e) so the softmax exp becomes a bare v_exp_f32
    const float qsc = 0.17677669529663687f * 1.4426950408889634f;
    proj_all_k<<<dim3(16, 4, 16), 256, 0, stream>>>(qn, cn, Wqt, Wkt, Wvt,
                                                    bq, bk, bv, Qb, Kb, Vt, qsc);

    attn_out_k<<<dim3(256), 1024, 0, stream>>>(Qb, Kb, Vt, Wot, bo, qraw, out);
}

// Round 19
// 64.568 us; speedup vs baseline: 1.0888x; 1.0041x over previous
//
#include <hip/hip_runtime.h>
#include <hip/hip_bf16.h>
#include <cstddef>

#define B_  8
#define CQ  256
#define CC  512
#define N_  1024   // Hq*Wq
#define HQ  32
#define WQ  32
#define NH  8
#define HD  32

typedef __bf16 bf16x8 __attribute__((ext_vector_type(8)));
typedef float f32x4 __attribute__((ext_vector_type(4)));
typedef float f32x16 __attribute__((ext_vector_type(16)));
typedef unsigned int uint4v __attribute__((ext_vector_type(4)));
typedef unsigned short ushort8 __attribute__((ext_vector_type(8)));
typedef unsigned short ushort4v __attribute__((ext_vector_type(4)));

__device__ __forceinline__ unsigned short f2bf(float x) {
    return __builtin_bit_cast(unsigned short, __float2bfloat16(x));
}
__device__ __forceinline__ float bf2f(unsigned short x) {
    return __bfloat162float(__builtin_bit_cast(__hip_bfloat16, x));
}
__device__ __forceinline__ bf16x8 ldb8(const unsigned short* p) {
    return __builtin_bit_cast(bf16x8, *(const ushort8*)p);
}

// ---------------------------------------------------------------------------
// prep_k (1280 blocks x 256), long-pole-first dispatch.
//   [0,256):    LN(query) -> qn bf16 + qraw bf16 (256 blocks, 32 pos each)
//   [256,768):  pool+LN(context) -> cn bf16
//   [768,1280): weight transpose f32->bf16
// ---------------------------------------------------------------------------
__global__ __launch_bounds__(256) void prep_k(
    const float* __restrict__ query, const float* __restrict__ context,
    const float* __restrict__ Wq, const float* __restrict__ Wk,
    const float* __restrict__ Wv, const float* __restrict__ Wo,
    const float* __restrict__ gq, const float* __restrict__ betq,
    const float* __restrict__ gc, const float* __restrict__ betc,
    __hip_bfloat16* __restrict__ Wqt, __hip_bfloat16* __restrict__ Wkt,
    __hip_bfloat16* __restrict__ Wvt, __hip_bfloat16* __restrict__ Wot,
    __hip_bfloat16* __restrict__ qn, __hip_bfloat16* __restrict__ cn,
    __hip_bfloat16* __restrict__ qraw) {
    __shared__ float T[32][33];
    __shared__ float SsA[32][16];
    __shared__ float S2A[32][16];
    __shared__ float SsB[32][32];
    __shared__ float S2B[32][32];
    __shared__ float Mu[32], Rs[32];

    const int bid = blockIdx.x;
    const int tid = threadIdx.x;

    if (bid < 256) {
        // --------- LN(query) + qraw: 256 blocks, 32 positions each ---------
        const int nt = bid & 31, b = bid >> 5;
        const int nq = tid & 7;
        const int cg = tid >> 3;
        const int ch0 = cg * 8;
        const int nb  = nt * 32 + 4 * nq;

        const float* Qb = query + ((size_t)b * CQ + ch0) * N_ + nb;
        float qv[32];
        float ps[4] = {0.f, 0.f, 0.f, 0.f};
        float p2[4] = {0.f, 0.f, 0.f, 0.f};
        #pragma unroll
        for (int i = 0; i < 8; ++i) {
            const float4 v = *(const float4*)(Qb + (size_t)i * N_);
            qv[4 * i + 0] = v.x; qv[4 * i + 1] = v.y;
            qv[4 * i + 2] = v.z; qv[4 * i + 3] = v.w;
            ps[0] += v.x; p2[0] += v.x * v.x;
            ps[1] += v.y; p2[1] += v.y * v.y;
            ps[2] += v.z; p2[2] += v.z * v.z;
            ps[3] += v.w; p2[3] += v.w * v.w;
        }
        #pragma unroll
        for (int i = 0; i < 8; ++i) {
            ushort4v o;
            o[0] = f2bf(qv[4 * i + 0]); o[1] = f2bf(qv[4 * i + 1]);
            o[2] = f2bf(qv[4 * i + 2]); o[3] = f2bf(qv[4 * i + 3]);
            *(ushort4v*)((unsigned short*)qraw + ((size_t)b * CQ + ch0 + i) * N_ + nb) = o;
        }
        #pragma unroll
        for (int j = 0; j < 4; ++j) {
            SsB[cg][4 * nq + j] = ps[j];
            S2B[cg][4 * nq + j] = p2[j];
        }
        __syncthreads();
        if (tid < 32) {
            float ts = 0.f, t2 = 0.f;
            #pragma unroll
            for (int i = 0; i < 32; ++i) { ts += SsB[i][tid]; t2 += S2B[i][tid]; }
            const float mu  = ts * (1.f / CQ);
            const float var = t2 * (1.f / CQ) - mu * mu;
            Mu[tid] = mu; Rs[tid] = rsqrtf(var + 1e-5f);
        }
        __syncthreads();
        #pragma unroll
        for (int j = 0; j < 4; ++j) {
            const float mu = Mu[4 * nq + j], rs = Rs[4 * nq + j];
            ushort8 o;
            #pragma unroll
            for (int i = 0; i < 8; ++i)
                o[i] = f2bf((qv[4 * i + j] - mu) * rs * gq[ch0 + i] + betq[ch0 + i]);
            *(ushort8*)((unsigned short*)qn + ((size_t)b * N_ + nb + j) * CQ + ch0) = o;
        }
    } else if (bid < 768) {
        // ------- pool + LN(context): float4 loads, register-resident -------
        const int u    = bid - 256;
        const int wqc2 = u & 1, hq = (u >> 1) & 31, b = u >> 6;
        const int pp   = tid & 7;
        const int cg   = tid >> 3;
        const int ch0  = cg * 16;

        const float* Cb = context + ((size_t)b * CC + ch0) * 4096
                        + (size_t)(2 * hq) * 64 + (32 * wqc2 + 4 * pp);
        float pv0[16], pv1[16];
        float ss0 = 0.f, ss1 = 0.f, s20 = 0.f, s21 = 0.f;
        #pragma unroll
        for (int i = 0; i < 16; ++i) {
            const float4 r0 = *(const float4*)(Cb + (size_t)i * 4096);
            const float4 r1 = *(const float4*)(Cb + (size_t)i * 4096 + 64);
            const float v0 = (r0.x + r0.y + r1.x + r1.y) * 0.25f;
            const float v1 = (r0.z + r0.w + r1.z + r1.w) * 0.25f;
            pv0[i] = v0; pv1[i] = v1;
            ss0 += v0; s20 += v0 * v0;
            ss1 += v1; s21 += v1 * v1;
        }
        SsA[cg][2 * pp]     = ss0; S2A[cg][2 * pp]     = s20;
        SsA[cg][2 * pp + 1] = ss1; S2A[cg][2 * pp + 1] = s21;
        __syncthreads();
        if (tid < 16) {
            float ts = 0.f, t2 = 0.f;
            #pragma unroll
            for (int i = 0; i < 32; ++i) { ts += SsA[i][tid]; t2 += S2A[i][tid]; }
            const float mu  = ts * (1.f / CC);
            const float var = t2 * (1.f / CC) - mu * mu;
            Mu[tid] = mu; Rs[tid] = rsqrtf(var + 1e-5f);
        }
        __syncthreads();
        const float mu0 = Mu[2 * pp],     rs0 = Rs[2 * pp];
        const float mu1 = Mu[2 * pp + 1], rs1 = Rs[2 * pp + 1];
        const int pos0 = hq * 32 + wqc2 * 16 + 2 * pp;
        unsigned short* dst = (unsigned short*)cn
            + ((size_t)b * N_ + pos0) * CC + ch0;
        ushort8 a0, a1, b0, b1;
        #pragma unroll
        for (int i = 0; i < 8; ++i) {
            a0[i] = f2bf((pv0[i] - mu0) * rs0 * gc[ch0 + i] + betc[ch0 + i]);
            b0[i] = f2bf((pv1[i] - mu1) * rs1 * gc[ch0 + i] + betc[ch0 + i]);
        }
        #pragma unroll
        for (int i = 0; i < 8; ++i) {
            a1[i] = f2bf((pv0[8 + i] - mu0) * rs0 * gc[ch0 + 8 + i] + betc[ch0 + 8 + i]);
            b1[i] = f2bf((pv1[8 + i] - mu1) * rs1 * gc[ch0 + 8 + i] + betc[ch0 + 8 + i]);
        }
        *(ushort8*)(dst)          = a0;
        *(ushort8*)(dst + 8)      = a1;
        *(ushort8*)(dst + CC)     = b0;
        *(ushort8*)(dst + CC + 8) = b1;
    } else {
        // ---------------- weight transpose (tail filler) ----------------
        const int u = bid - 768;
        const int x = u & 15, y = (u >> 4) & 7, z = u >> 7;
        const float* W; __hip_bfloat16* Wt; int K;
        switch (z) {
            case 0: W = Wq; Wt = Wqt; K = CQ; break;
            case 1: W = Wk; Wt = Wkt; K = CC; break;
            case 2: W = Wv; Wt = Wvt; K = CC; break;
            default: W = Wo; Wt = Wot; K = CQ; break;
        }
        const int k0 = x * 32;
        if (k0 >= K) return;
        const int c0 = y * 32;
        const int tx = tid & 31, ty = tid >> 5;
        #pragma unroll
        for (int i = 0; i < 4; ++i) {
            const int r = ty + 8 * i;
            T[r][tx] = W[(size_t)(k0 + r) * CQ + c0 + tx];
        }
        __syncthreads();
        #pragma unroll
        for (int i = 0; i < 4; ++i) {
            const int r = ty + 8 * i;
            Wt[(size_t)(c0 + r) * K + k0 + tx] = __float2bfloat16(T[tx][r]);
        }
    }
}

// ---------------------------------------------------------------------------
// proj_all_k: Q projection (z>=8) and fused K+V projection (z<8), reg-staged
// prefetch, V columns PERMUTED per 16-block. grid (16,4,16).
// ---------------------------------------------------------------------------
__global__ __launch_bounds__(256) void proj_all_k(
    const __hip_bfloat16* __restrict__ qn, const __hip_bfloat16* __restrict__ cn,
    const __hip_bfloat16* __restrict__ Wqt, const __hip_bfloat16* __restrict__ Wkt,
    const __hip_bfloat16* __restrict__ Wvt,
    const float* __restrict__ bq, const float* __restrict__ bk,
    const float* __restrict__ bv,
    __hip_bfloat16* __restrict__ Qb, __hip_bfloat16* __restrict__ Kb,
    __hip_bfloat16* __restrict__ Vt, float qsc) {
    __shared__ unsigned short As[64][40];
    __shared__ unsigned short B1[64][40];
    __shared__ unsigned short B2[64][40];

    const int zz = blockIdx.z;
    const int n0 = blockIdx.x * 64;
    const int c0 = blockIdx.y * 64;
    const int tid = threadIdx.x;
    const int wid = tid >> 6, lane = tid & 63;
    const int lg = lane >> 4, ln = lane & 15;
    const int wn0 = (wid & 1) * 32, wc0 = (wid >> 1) * 32;
    const int sr = tid >> 2;
    const int sk = (tid & 3) * 8;

    if (zz >= 8) {
        const int b = zz - 8;
        const unsigned short* Ab = (const unsigned short*)qn + ((size_t)b * N_ + n0) * CQ;
        const unsigned short* Wb = (const unsigned short*)Wqt + (size_t)c0 * CQ;
        f32x4 acc[2][2] = {};
        ushort8 ra = *(const ushort8*)(Ab + (size_t)sr * CQ + sk);
        ushort8 rw = *(const ushort8*)(Wb + (size_t)sr * CQ + sk);
        for (int t = 0; t < 8; ++t) {
            *(ushort8*)&As[sr][sk] = ra;
            *(ushort8*)&B1[sr][sk] = rw;
            __syncthreads();
            if (t < 7) {
                ra = *(const ushort8*)(Ab + (size_t)sr * CQ + (t + 1) * 32 + sk);
                rw = *(const ushort8*)(Wb + (size_t)sr * CQ + (t + 1) * 32 + sk);
            }
            bf16x8 a[2], w[2];
            #pragma unroll
            for (int i = 0; i < 2; ++i) a[i] = ldb8(&As[wn0 + 16 * i + ln][8 * lg]);
            #pragma unroll
            for (int j = 0; j < 2; ++j) w[j] = ldb8(&B1[wc0 + 16 * j + ln][8 * lg]);
            #pragma unroll
            for (int i = 0; i < 2; ++i)
                #pragma unroll
                for (int j = 0; j < 2; ++j)
                    acc[i][j] = __builtin_amdgcn_mfma_f32_16x16x32_bf16(a[i], w[j], acc[i][j], 0, 0, 0);
            __syncthreads();
        }
        #pragma unroll
        for (int j = 0; j < 2; ++j) {
            const int co = c0 + wc0 + 16 * j + ln;
            const int h = co >> 5, d = co & 31;
            const float bb = bq[co];
            #pragma unroll
            for (int i = 0; i < 2; ++i)
                #pragma unroll
                for (int r = 0; r < 4; ++r) {
                    const int n = n0 + wn0 + 16 * i + 4 * lg + r;
                    Qb[(((size_t)b * NH + h) * N_ + n) * HD + d] =
                        __float2bfloat16((acc[i][j][r] + bb) * qsc);
                }
        }
    } else {
        const int b = zz;
        const unsigned short* Ab  = (const unsigned short*)cn + ((size_t)b * N_ + n0) * CC;
        const unsigned short* Wkb = (const unsigned short*)Wkt + (size_t)c0 * CC;
        const unsigned short* Wvb = (const unsigned short*)Wvt + (size_t)c0 * CC;
        f32x4 accK[2][2] = {};
        f32x4 accV[2][2] = {};
        ushort8 ra = *(const ushort8*)(Ab  + (size_t)sr * CC + sk);
        ushort8 rk = *(const ushort8*)(Wkb + (size_t)sr * CC + sk);
        ushort8 rv = *(const ushort8*)(Wvb + (size_t)sr * CC + sk);
        for (int t = 0; t < 16; ++t) {
            *(ushort8*)&As[sr][sk] = ra;
            *(ushort8*)&B1[sr][sk] = rk;
            *(ushort8*)&B2[sr][sk] = rv;
            __syncthreads();
            if (t < 15) {
                ra = *(const ushort8*)(Ab  + (size_t)sr * CC + (t + 1) * 32 + sk);
                rk = *(const ushort8*)(Wkb + (size_t)sr * CC + (t + 1) * 32 + sk);
                rv = *(const ushort8*)(Wvb + (size_t)sr * CC + (t + 1) * 32 + sk);
            }
            bf16x8 a[2], wk[2], wv[2];
            #pragma unroll
            for (int i = 0; i < 2; ++i) {
                a[i]  = ldb8(&As[wn0 + 16 * i + ln][8 * lg]);
                wk[i] = ldb8(&B1[wc0 + 16 * i + ln][8 * lg]);
                wv[i] = ldb8(&B2[wc0 + 16 * i + ln][8 * lg]);
            }
            #pragma unroll
            for (int i = 0; i < 2; ++i)
                #pragma unroll
                for (int j = 0; j < 2; ++j) {
                    accK[i][j] = __builtin_amdgcn_mfma_f32_16x16x32_bf16(a[i], wk[j], accK[i][j], 0, 0, 0);
                    accV[i][j] = __builtin_amdgcn_mfma_f32_16x16x32_bf16(a[i], wv[j], accV[i][j], 0, 0, 0);
                }
            __syncthreads();
        }
        #pragma unroll
        for (int j = 0; j < 2; ++j) {
            const int co = c0 + wc0 + 16 * j + ln;
            const int h = co >> 5, d = co & 31;
            const float bbk = bk[co], bbv = bv[co];
            #pragma unroll
            for (int i = 0; i < 2; ++i) {
                const int nb = n0 + wn0 + 16 * i + 4 * lg;
                #pragma unroll
                for (int r = 0; r < 4; ++r)
                    Kb[(((size_t)b * NH + h) * N_ + nb + r) * HD + d] =
                        __float2bfloat16(accK[i][j][r] + bbk);
                ushort4v o;
                #pragma unroll
                for (int r = 0; r < 4; ++r) o[r] = f2bf(accV[i][j][r] + bbv);
                const int g  = (nb >> 2) & 3;
                const int gp = ((g & 1) << 1) | (g >> 1);
                const int nbp = (nb & ~15) | (gp << 2);
                *(ushort4v*)((unsigned short*)Vt + (((size_t)b * NH + h) * HD + d) * N_ + nbp) = o;
            }
        }
    }
}

// ---------------------------------------------------------------------------
// attn_out_k: FUSED attention + output projection + bias + residual.
// 256 blocks x 1024 threads (1 block/CU). Block = 32 q-rows x ALL 8 heads x
// both kv-halves: wave wid = (kvh<<3)|h. O tile lands in LDS (32x264 bf16);
// after one barrier the same 16 waves do the O-projection (A from LDS, Wot
// rows direct from L2), writing out f32 (B,CQ,N) with bias + bf16 residual.
// ---------------------------------------------------------------------------
__global__ __launch_bounds__(1024) void attn_out_k(
    const __hip_bfloat16* __restrict__ Q,
    const __hip_bfloat16* __restrict__ K,
    const __hip_bfloat16* __restrict__ Vt,
    const __hip_bfloat16* __restrict__ Wot,
    const float* __restrict__ bo,
    const __hip_bfloat16* __restrict__ qraw,
    float* __restrict__ out) {
    __shared__ float accS[8][64][20];         // 40 KB: kvh=1 partials per head
    __shared__ float lwS[8][64];              //  2 KB
    __shared__ unsigned short ObL[32][264];   // 16.5 KB: O tile [n][co]

    // XCD swizzle: 32 consecutive q-tiles of a b per XCD (256 blocks, 8 XCDs)
    const int lin = blockIdx.x;
    const int eff = (lin & 7) * 32 + (lin >> 3);
    const int qt  = eff & 31;
    const int b   = eff >> 5;
    const int wid  = threadIdx.x >> 6;    // 0..15
    const int lane = threadIdx.x & 63;
    const int l31  = lane & 31;
    const int hh   = lane >> 5;
    const int h    = wid & 7;
    const int kvh  = wid >> 3;
    const int q0   = qt * 32;
    const int bh   = b * NH + h;

    const unsigned short* Qp  = (const unsigned short*)Q + ((size_t)bh * N_ + q0) * HD;
    const unsigned short* Kbb = (const unsigned short*)K + (size_t)bh * N_ * HD;
    const unsigned short* Vb  = (const unsigned short*)Vt + ((size_t)bh * HD + l31) * N_;

    bf16x8 qB[2];
    #pragma unroll
    for (int m = 0; m < 2; ++m)
        qB[m] = ldb8(Qp + (size_t)l31 * HD + 16 * m + 8 * hh);

    const f32x16 Z = {0.f,0.f,0.f,0.f,0.f,0.f,0.f,0.f,
                      0.f,0.f,0.f,0.f,0.f,0.f,0.f,0.f};
    f32x16 acc = Z;
    float ls0 = 0.f, ls1 = 0.f, ls2 = 0.f, ls3 = 0.f;

    const int kvbase = kvh * 512;
    const unsigned short* kp = Kbb + (size_t)(kvbase + l31) * HD + 8 * hh;
    const unsigned short* vp = Vb + kvbase + 8 * hh;

    bf16x8 kaA[2][4];
    #pragma unroll
    for (int j = 0; j < 4; ++j)
        kaA[0][j] = ldb8(kp + (j >> 1) * 1024 + (j & 1) * 16);

    #pragma unroll
    for (int st = 0; st < 8; ++st) {
        const int cur = st & 1;
        bf16x8 va[4];
        #pragma unroll
        for (int j = 0; j < 4; ++j)
            va[j] = ldb8(vp + st * 64 + 16 * j);
        if (st < 7) {
            const unsigned short* kp2 = kp + (size_t)(st + 1) * 2048;
            #pragma unroll
            for (int j = 0; j < 4; ++j)
                kaA[cur ^ 1][j] = ldb8(kp2 + (j >> 1) * 1024 + (j & 1) * 16);
        }

        f32x16 s0, s1;
        s0 = __builtin_amdgcn_mfma_f32_32x32x16_bf16(kaA[cur][0], qB[0], Z, 0, 0, 0);
        s0 = __builtin_amdgcn_mfma_f32_32x32x16_bf16(kaA[cur][1], qB[1], s0, 0, 0, 0);
        s1 = __builtin_amdgcn_mfma_f32_32x32x16_bf16(kaA[cur][2], qB[0], Z, 0, 0, 0);
        s1 = __builtin_amdgcn_mfma_f32_32x32x16_bf16(kaA[cur][3], qB[1], s1, 0, 0, 0);

        unsigned int pk[2][4][2];
        #pragma unroll
        for (int T = 0; T < 2; ++T) {
            float p[16];
            #pragma unroll
            for (int r = 0; r < 16; ++r)
                p[r] = __builtin_amdgcn_exp2f(T == 0 ? s0[r] : s1[r]);
            #pragma unroll
            for (int r = 0; r < 16; r += 4) {
                ls0 += p[r]; ls1 += p[r + 1]; ls2 += p[r + 2]; ls3 += p[r + 3];
            }
            #pragma unroll
            for (int c = 0; c < 4; ++c) {
                asm("v_cvt_pk_bf16_f32 %0, %1, %2"
                    : "=v"(pk[T][c][0]) : "v"(p[4 * c]), "v"(p[4 * c + 1]));
                asm("v_cvt_pk_bf16_f32 %0, %1, %2"
                    : "=v"(pk[T][c][1]) : "v"(p[4 * c + 2]), "v"(p[4 * c + 3]));
            }
        }

        #pragma unroll
        for (int w = 0; w < 4; ++w) {
            const int T = w >> 1, cp = w & 1;
            uint4v fu = {pk[T][2 * cp][0], pk[T][2 * cp][1],
                         pk[T][2 * cp + 1][0], pk[T][2 * cp + 1][1]};
            const bf16x8 pa = __builtin_bit_cast(bf16x8, fu);
            acc = __builtin_amdgcn_mfma_f32_32x32x16_bf16(pa, va[w], acc, 0, 0, 0);
        }
    }

    const float lsum = (ls0 + ls1) + (ls2 + ls3);
    const float lw = lsum + __shfl_xor(lsum, 32);

    if (kvh == 1) {
        #pragma unroll
        for (int r4 = 0; r4 < 4; ++r4) {
            float4 v = {acc[4 * r4], acc[4 * r4 + 1], acc[4 * r4 + 2], acc[4 * r4 + 3]};
            *(float4*)&accS[h][lane][4 * r4] = v;
        }
        lwS[h][lane] = lw;
    }
    __syncthreads();
    if (kvh == 0) {
        const float linv = 1.0f / (lw + lwS[h][lane]);
        #pragma unroll
        for (int r = 0; r < 16; ++r) {
            const int ql = (r & 3) + 8 * (r >> 2) + 4 * hh;
            const float vv = (acc[r] + accS[h][lane][r]) * __shfl(linv, ql);
            ObL[ql][h * HD + l31] = f2bf(vv);
        }
    }
    __syncthreads();

    // ---- O-projection: 32n x 256co; wave wid handles co [16*wid, 16*wid+16)
    const int lg = lane >> 4, ln = lane & 15;
    const int co0 = wid * 16;
    const unsigned short* Wb = (const unsigned short*)Wot + (size_t)co0 * CQ;

    f32x4 acc2[2] = {};
    #pragma unroll
    for (int t = 0; t < 8; ++t) {
        const int k0 = t * 32;
        const bf16x8 w = ldb8(Wb + (size_t)ln * CQ + k0 + 8 * lg);
        #pragma unroll
        for (int i = 0; i < 2; ++i) {
            const bf16x8 a = ldb8(&ObL[16 * i + ln][k0 + 8 * lg]);
            acc2[i] = __builtin_amdgcn_mfma_f32_16x16x32_bf16(a, w, acc2[i], 0, 0, 0);
        }
    }

    const int co = co0 + ln;
    const float bb = bo[co];
    #pragma unroll
    for (int i = 0; i < 2; ++i) {
        const int nb = q0 + 16 * i + 4 * lg;
        const ushort4v res = *(const ushort4v*)((const unsigned short*)qraw
            + ((size_t)b * CQ + co) * N_ + nb);
        float4 o;
        o.x = acc2[i][0] + bb + bf2f(res[0]);
        o.y = acc2[i][1] + bb + bf2f(res[1]);
        o.z = acc2[i][2] + bb + bf2f(res[2]);
        o.w = acc2[i][3] + bb + bf2f(res[3]);
        *(float4*)&out[((size_t)b * CQ + co) * N_ + nb] = o;
    }
}

// ---------------------------------------------------------------------------
extern "C" void kernel_launch(void* const* d_in, const int* in_sizes, int n_in,
                              void* d_out, int out_size, void* d_ws, size_t ws_size,
                              hipStream_t stream) {
    const float* query   = (const float*)d_in[0];
    const float* context = (const float*)d_in[1];
    const float* Wq = (const float*)d_in[2];
    const float* bq = (const float*)d_in[3];
    const float* Wk = (const float*)d_in[4];
    const float* bk = (const float*)d_in[5];
    const float* Wv = (const float*)d_in[6];
    const float* bv = (const float*)d_in[7];
    const float* Wo = (const float*)d_in[8];
    const float* bo = (const float*)d_in[9];
    const float* gq   = (const float*)d_in[10];
    const float* betq = (const float*)d_in[11];
    const float* gc   = (const float*)d_in[12];
    const float* betc = (const float*)d_in[13];
    float* out = (float*)d_out;

    char* w = (char*)d_ws;
    __hip_bfloat16* qn   = (__hip_bfloat16*)w;  w += (size_t)B_ * N_ * CQ * 2;
    __hip_bfloat16* cn   = (__hip_bfloat16*)w;  w += (size_t)B_ * N_ * CC * 2;
    __hip_bfloat16* qraw = (__hip_bfloat16*)w;  w += (size_t)B_ * CQ * N_ * 2;
    __hip_bfloat16* Qb   = (__hip_bfloat16*)w;  w += (size_t)B_ * NH * N_ * HD * 2;
    __hip_bfloat16* Kb   = (__hip_bfloat16*)w;  w += (size_t)B_ * NH * N_ * HD * 2;
    __hip_bfloat16* Vt   = (__hip_bfloat16*)w;  w += (size_t)B_ * NH * HD * N_ * 2;
    __hip_bfloat16* Wqt  = (__hip_bfloat16*)w;  w += (size_t)CQ * CQ * 2;
    __hip_bfloat16* Wkt  = (__hip_bfloat16*)w;  w += (size_t)CQ * CC * 2;
    __hip_bfloat16* Wvt  = (__hip_bfloat16*)w;  w += (size_t)CQ * CC * 2;
    __hip_bfloat16* Wot  = (__hip_bfloat16*)w;  w += (size_t)CQ * CQ * 2;

    prep_k<<<dim3(1280), 256, 0, stream>>>(query, context, Wq, Wk, Wv, Wo,
                                           gq, betq, gc, betc,
                                           Wqt, Wkt, Wvt, Wot, qn, cn, qraw);

    // scale includes log2(e) so the softmax exp becomes a bare v_exp_f32
    const float qsc = 0.17677669529663687f * 1.4426950408889634f;
    proj_all_k<<<dim3(16, 4, 16), 256, 0, stream>>>(qn, cn, Wqt, Wkt, Wvt,
                                                    bq, bk, bv, Qb, Kb, Vt, qsc);

    attn_out_k<<<dim3(256), 1024, 0, stream>>>(Qb, Kb, Vt, Wot, bo, qraw, out);
}